// Round 6
// baseline (398.706 us; speedup 1.0000x reference)
//
#include <hip/hip_runtime.h>
#include <hip/hip_bf16.h>
#include <cstdint>
#include <type_traits>

typedef __attribute__((ext_vector_type(8))) short short8;
typedef __attribute__((ext_vector_type(4))) float floatx4;

constexpr int S_LEN = 2048;
constexpr float ATTN_SCALE = 0.08838834764831845f;  // 128^-0.5
constexpr float LOG2E = 1.4426950408889634f;
constexpr float CP = ATTN_SCALE * LOG2E;            // fold scale into exp2 arg
constexpr float THRR = 5.0f / CP;                   // defer-max threshold (raw units)

// ---------------------------------------------------------------- async G->LDS
__device__ __forceinline__ void gl_lds16(const void* gp, void* lp) {
  __builtin_amdgcn_global_load_lds(
      (__attribute__((address_space(1))) void*)(uintptr_t)gp,
      (__attribute__((address_space(3))) void*)lp,
      16, 0, 0);
}

// --------------------------------------------------------------------- RoPE
__device__ __forceinline__ void rope8(short8 x0, short8 x1, const float* ca,
                                      const float* sa, const float* cb,
                                      const float* sb, short8& y0, short8& y1) {
#pragma unroll
  for (int e = 0; e < 8; ++e) {
    union { short s; __hip_bfloat16 h; } u0, u1, w0, w1;
    u0.s = x0[e]; u1.s = x1[e];
    float f0 = __bfloat162float(u0.h), f1 = __bfloat162float(u1.h);
    int j = e >> 1;
    w0.h = __float2bfloat16(f0 * ca[j] - f1 * sa[j]);
    w1.h = __float2bfloat16(f1 * cb[j] + f0 * sb[j]);
    y0[e] = w0.s; y1[e] = w1.s;
  }
}

// ------------------------------------------------------------- fused prologue
__device__ __forceinline__ void tr32(const float* __restrict__ src,
                                     __hip_bfloat16* __restrict__ dst,
                                     int blk, int nblk_x, int N, int tid,
                                     float (*tile)[33]) {
  int n0 = (blk % nblk_x) * 32, k0 = (blk / nblk_x) * 32;
  int tx = tid & 31, ty = tid >> 5;   // (32, 8)
#pragma unroll
  for (int i = ty; i < 32; i += 8)
    tile[i][tx] = src[(size_t)(k0 + i) * N + n0 + tx];
  __syncthreads();
#pragma unroll
  for (int i = ty; i < 32; i += 8)
    dst[(size_t)(n0 + i) * 2048 + k0 + tx] = __float2bfloat16(tile[tx][i]);
}

__global__ void prep_kernel(const float* __restrict__ x,
                            const float* __restrict__ Wq,
                            const float* __restrict__ Wk,
                            const float* __restrict__ Wv,
                            const float* __restrict__ Wo,
                            __hip_bfloat16* __restrict__ xb,
                            __hip_bfloat16* __restrict__ wqkvt,
                            __hip_bfloat16* __restrict__ wot) {
  __shared__ float tile[32][33];
  int bx = blockIdx.x, tid = threadIdx.x;
  if (bx < 8192) {
    int i = bx * 256 + tid;           // 2097152 float4s exactly
    float4 f = reinterpret_cast<const float4*>(x)[i];
    union { unsigned long long u64; __hip_bfloat16 h[4]; } u;
    u.h[0] = __float2bfloat16(f.x);
    u.h[1] = __float2bfloat16(f.y);
    u.h[2] = __float2bfloat16(f.z);
    u.h[3] = __float2bfloat16(f.w);
    reinterpret_cast<unsigned long long*>(xb)[i] = u.u64;
  } else if (bx < 12288) {
    tr32(Wq, wqkvt, bx - 8192, 64, 2048, tid, tile);
  } else if (bx < 13312) {
    tr32(Wk, wqkvt + 2048 * 2048, bx - 12288, 16, 512, tid, tile);
  } else if (bx < 14336) {
    tr32(Wv, wqkvt + 2560 * 2048, bx - 13312, 16, 512, tid, tile);
  } else {
    tr32(Wo, wot, bx - 14336, 64, 2048, tid, tile);
  }
}

// ===================================================================
// 256x256-tile 8-phase GEMM core (unchanged, proven). BK=64, 8 waves (2Mx4N),
// 128 KiB dbuf LDS, counted vmcnt(4), setprio around MFMA clusters.
// ===================================================================
__device__ __forceinline__ void gemm256_core(
    const __hip_bfloat16* __restrict__ Ab,   // A + m0*K, row-major [.][K]
    const __hip_bfloat16* __restrict__ Bb,   // Bt + n0*K, row-major [.][K]
    const int K, __hip_bfloat16* lds, floatx4 (&acc)[8][4]) {
  const int tid = threadIdx.x;
  const int wave = tid >> 6, lane = tid & 63;
  const int quad = lane >> 4, l15 = lane & 15;
  const int wm = wave >> 2, wn = wave & 3;
  const int nt = K >> 6;
  const int u2 = wave * 2;

  auto stA = [&](int tt, int h) {
    __hip_bfloat16* dst = lds + (tt & 1) * 32768;
    const int k0 = tt << 6;
#pragma unroll
    for (int j = 0; j < 2; ++j) {
      const int kc = (u2 + j) >> 1, rb = (u2 + j) & 1;
      gl_lds16(Ab + (size_t)(h * 128 + rb * 64 + lane) * K + k0 + kc * 8,
               dst + (kc * 256 + h * 128 + rb * 64) * 8);
    }
  };
  auto stB = [&](int tt, int h) {
    __hip_bfloat16* dst = lds + (tt & 1) * 32768 + 16384;
    const int k0 = tt << 6;
#pragma unroll
    for (int j = 0; j < 2; ++j) {
      const int kc = (u2 + j) >> 1, rb = (u2 + j) & 1;
      gl_lds16(Bb + (size_t)(h * 128 + rb * 64 + lane) * K + k0 + kc * 8,
               dst + (kc * 256 + h * 128 + rb * 64) * 8);
    }
  };

  // prologue: tile0 fully + tile1 B halves (A1 staged in tile0 ph0/ph1)
  stA(0, 0); stA(0, 1); stB(0, 0); stB(0, 1);
  if (nt > 1) { stB(1, 0); stB(1, 1); }
  asm volatile("s_waitcnt vmcnt(4)" ::: "memory");   // tile0's 8 loads landed
  __builtin_amdgcn_s_barrier();

  const int abase = (quad * 256 + wm * 128 + l15) * 8;
  const int bbase = (quad * 256 + wn * 64 + l15) * 8;

#pragma unroll 2
  for (int t = 0; t < nt; ++t) {
    const __hip_bfloat16* Al = lds + (t & 1) * 32768;
    const __hip_bfloat16* Bl = Al + 16384;
    short8 b[2][4];
#pragma unroll
    for (int q = 0; q < 4; ++q) {
      short8 a[2][2];
#pragma unroll
      for (int kk = 0; kk < 2; ++kk) {
        if (q == 0) {
#pragma unroll
          for (int ni = 0; ni < 4; ++ni)
            b[kk][ni] = *(const short8*)&Bl[kk * 8192 + bbase + ni * 128];
        }
#pragma unroll
        for (int mi = 0; mi < 2; ++mi)
          a[kk][mi] = *(const short8*)&Al[kk * 8192 + abase + (2 * q + mi) * 128];
      }
      if (q == 0)      { if (t + 1 < nt) stA(t + 1, 0); }
      else if (q == 1) { if (t + 1 < nt) stA(t + 1, 1); }
      else if (q == 2) { if (t + 2 < nt) stB(t + 2, 0); }
      else             { if (t + 2 < nt) stB(t + 2, 1); }
      __builtin_amdgcn_s_barrier();
      asm volatile("s_waitcnt lgkmcnt(0)" ::: "memory");
      __builtin_amdgcn_sched_barrier(0);    // rule #18: pin reads above MFMAs
      __builtin_amdgcn_s_setprio(1);
#pragma unroll
      for (int kk = 0; kk < 2; ++kk)
#pragma unroll
        for (int mi = 0; mi < 2; ++mi)
#pragma unroll
          for (int ni = 0; ni < 4; ++ni)
            acc[2 * q + mi][ni] = __builtin_amdgcn_mfma_f32_16x16x32_bf16(
                a[kk][mi], b[kk][ni], acc[2 * q + mi][ni], 0, 0, 0);
      __builtin_amdgcn_s_setprio(0);
      if (q == 3) {
        if (t + 2 < nt) asm volatile("s_waitcnt vmcnt(4)" ::: "memory");
        else            asm volatile("s_waitcnt vmcnt(0)" ::: "memory");
      }
      __builtin_amdgcn_s_barrier();
    }
  }
  asm volatile("" ::: "memory");   // fence before LDS reuse in epilogue
}

// ===================================================================
// 256x128-tile 2-phase GEMM core (unchanged, proven).
// ===================================================================
__device__ __forceinline__ void gemm_256x128_core(
    const __hip_bfloat16* __restrict__ Ab,
    const __hip_bfloat16* __restrict__ Bb,
    const int K, __hip_bfloat16* lds, floatx4 (&acc)[4][4]) {
  const int tid = threadIdx.x;
  const int wave = tid >> 6, lane = tid & 63;
  const int quad = lane >> 4, l15 = lane & 15;
  const int wm = wave >> 1, wn = wave & 1;
  const int nt = K >> 6;

  auto stA = [&](int tt, int c) {     // c in 0..3
    __hip_bfloat16* dst = lds + (tt & 1) * 24576;
    const int k0 = tt << 6;
    const int i = c * 8 + wave;       // 0..31: kc = i>>2, rowblk = i&3
    const int kc = i >> 2, rb = i & 3;
    gl_lds16(Ab + (size_t)(rb * 64 + lane) * K + k0 + kc * 8,
             dst + (kc * 256 + rb * 64) * 8);
  };
  auto stB = [&](int tt, int c) {     // c in 0..1
    __hip_bfloat16* dst = lds + (tt & 1) * 24576 + 16384;
    const int k0 = tt << 6;
    const int i = c * 8 + wave;       // 0..15: kc = i>>1, rowblk = i&1
    const int kc = i >> 1, rb = i & 1;
    gl_lds16(Bb + (size_t)(rb * 64 + lane) * K + k0 + kc * 8,
             dst + (kc * 128 + rb * 64) * 8);
  };

  stA(0, 0); stA(0, 1); stA(0, 2); stA(0, 3);
  stB(0, 0); stB(0, 1);
  if (nt > 1) {
    stB(1, 0); stB(1, 1);
    asm volatile("s_waitcnt vmcnt(2)" ::: "memory");
  } else {
    asm volatile("s_waitcnt vmcnt(0)" ::: "memory");
  }
  __builtin_amdgcn_s_barrier();

  const int abase = (quad * 256 + wm * 64 + l15) * 8;
  const int bbase = (quad * 128 + wn * 64 + l15) * 8;

#pragma unroll 2
  for (int t = 0; t < nt; ++t) {
    const __hip_bfloat16* Al = lds + (t & 1) * 24576;
    const __hip_bfloat16* Bl = Al + 16384;
    short8 b[2][4], a[2][2];
    // ---- phase 0: mi 0,1 (B frags read once per tile, reused in ph1)
#pragma unroll
    for (int kk = 0; kk < 2; ++kk) {
#pragma unroll
      for (int ni = 0; ni < 4; ++ni)
        b[kk][ni] = *(const short8*)&Bl[kk * 4096 + bbase + ni * 128];
#pragma unroll
      for (int mi = 0; mi < 2; ++mi)
        a[kk][mi] = *(const short8*)&Al[kk * 8192 + abase + mi * 128];
    }
    if (t + 1 < nt) { stA(t + 1, 0); stA(t + 1, 1); }
    __builtin_amdgcn_s_barrier();
    asm volatile("s_waitcnt lgkmcnt(0)" ::: "memory");
    __builtin_amdgcn_sched_barrier(0);
    __builtin_amdgcn_s_setprio(1);
#pragma unroll
    for (int kk = 0; kk < 2; ++kk)
#pragma unroll
      for (int mi = 0; mi < 2; ++mi)
#pragma unroll
        for (int ni = 0; ni < 4; ++ni)
          acc[mi][ni] = __builtin_amdgcn_mfma_f32_16x16x32_bf16(
              a[kk][mi], b[kk][ni], acc[mi][ni], 0, 0, 0);
    __builtin_amdgcn_s_setprio(0);
    __builtin_amdgcn_s_barrier();
    // ---- phase 1: mi 2,3
#pragma unroll
    for (int kk = 0; kk < 2; ++kk)
#pragma unroll
      for (int mi = 0; mi < 2; ++mi)
        a[kk][mi] = *(const short8*)&Al[kk * 8192 + abase + (2 + mi) * 128];
    if (t + 1 < nt) { stA(t + 1, 2); stA(t + 1, 3); }
    if (t + 2 < nt) { stB(t + 2, 0); stB(t + 2, 1); }
    __builtin_amdgcn_s_barrier();
    asm volatile("s_waitcnt lgkmcnt(0)" ::: "memory");
    __builtin_amdgcn_sched_barrier(0);
    __builtin_amdgcn_s_setprio(1);
#pragma unroll
    for (int kk = 0; kk < 2; ++kk)
#pragma unroll
      for (int mi = 0; mi < 2; ++mi)
#pragma unroll
        for (int ni = 0; ni < 4; ++ni)
          acc[2 + mi][ni] = __builtin_amdgcn_mfma_f32_16x16x32_bf16(
              a[kk][mi], b[kk][ni], acc[2 + mi][ni], 0, 0, 0);
    __builtin_amdgcn_s_setprio(0);
    if (t + 2 < nt) asm volatile("s_waitcnt vmcnt(2)" ::: "memory");
    else            asm volatile("s_waitcnt vmcnt(0)" ::: "memory");
    __builtin_amdgcn_s_barrier();
  }
  asm volatile("" ::: "memory");
}

// ------------------------------------------------------------ QKV GEMM (fused)
__global__ __launch_bounds__(512, 2) void qkv_gemm_kernel(
    const __hip_bfloat16* __restrict__ A,
    const __hip_bfloat16* __restrict__ Bt,
    __hip_bfloat16* __restrict__ qbuf,
    __hip_bfloat16* __restrict__ kbuf,
    __hip_bfloat16* __restrict__ vbuf,
    const float* __restrict__ cosb,
    const float* __restrict__ sinb) {
  constexpr int K = 2048;
  __shared__ __align__(16) __hip_bfloat16 lds[65536];  // 128 KiB
  const int tid = threadIdx.x;
  const int m0 = blockIdx.y * 256, n0 = blockIdx.x * 256;

  floatx4 acc[8][4] = {};
  gemm256_core(A + (size_t)m0 * K, Bt + (size_t)n0 * K, K, lds, acc);

  const int wave = tid >> 6, lane = tid & 63;
  const int quad = lane >> 4, l15 = lane & 15;
  const int wm = wave >> 2, wn = wave & 3;
  const bool isv = (n0 >= 2560);
  short* lds2 = (short*)lds;                       // [256][256] bf16 = 128 KB
#pragma unroll
  for (int mi = 0; mi < 8; ++mi)
#pragma unroll
    for (int ni = 0; ni < 4; ++ni)
#pragma unroll
      for (int r = 0; r < 4; ++r) {
        int row = wm * 128 + mi * 16 + quad * 4 + r;  // C/D: row = quad*4+reg
        int col = wn * 64 + ni * 16 + l15;            //      col = lane&15
        union { short s; __hip_bfloat16 h; } u;
        u.h = __float2bfloat16(acc[mi][ni][r]);
        if (isv) lds2[col * 256 + row] = u.s;         // V stored transposed
        else     lds2[row * 256 + col] = u.s;
      }
  __syncthreads();

  const int c16 = tid & 15, hh = c16 >> 3, c8 = c16 & 7;
  const int rid = tid >> 4, d0 = c8 * 8;
  if (n0 < 2048) {
    // ---- Q: rope + row-major coalesced write (2 heads per tile)
#pragma unroll
    for (int j = 0; j < 8; ++j) {
      int rr = rid + 32 * j;
      int rowg = m0 + rr;
      int s = rowg & (S_LEN - 1);
      float ca[4], sa[4], cb[4], sb[4];
      *(float4*)ca = *(const float4*)&cosb[s * 64 + c8 * 4];
      *(float4*)sa = *(const float4*)&sinb[s * 64 + c8 * 4];
      *(float4*)cb = *(const float4*)&cosb[s * 64 + 32 + c8 * 4];
      *(float4*)sb = *(const float4*)&sinb[s * 64 + 32 + c8 * 4];
      short8 x0 = *(const short8*)&lds2[rr * 256 + hh * 128 + d0];
      short8 x1 = *(const short8*)&lds2[rr * 256 + hh * 128 + 64 + d0];
      short8 y0, y1;
      rope8(x0, x1, ca, sa, cb, sb, y0, y1);
      *(short8*)(qbuf + (size_t)rowg * 2048 + n0 + hh * 128 + d0) = y0;
      *(short8*)(qbuf + (size_t)rowg * 2048 + n0 + hh * 128 + 64 + d0) = y1;
    }
  } else if (!isv) {
    // ---- K: rope + chunk-transposed tile write (2 kv-heads per tile)
    const int kvh = ((n0 - 2048) >> 7) + hh;
#pragma unroll
    for (int j = 0; j < 8; ++j) {
      int rr = rid + 32 * j;
      int rowg = m0 + rr;
      int s = rowg & (S_LEN - 1), bb = rowg >> 11;
      int kv = s & 63;
      size_t tb = ((size_t)(bb * 4 + kvh) * 32 + (s >> 6)) * 8192;
      float ca[4], sa[4], cb[4], sb[4];
      *(float4*)ca = *(const float4*)&cosb[s * 64 + c8 * 4];
      *(float4*)sa = *(const float4*)&sinb[s * 64 + c8 * 4];
      *(float4*)cb = *(const float4*)&cosb[s * 64 + 32 + c8 * 4];
      *(float4*)sb = *(const float4*)&sinb[s * 64 + 32 + c8 * 4];
      short8 x0 = *(const short8*)&lds2[rr * 256 + hh * 128 + d0];
      short8 x1 = *(const short8*)&lds2[rr * 256 + hh * 128 + 64 + d0];
      short8 y0, y1;
      rope8(x0, x1, ca, sa, cb, sb, y0, y1);
      *(short8*)(kbuf + tb + (size_t)c8 * 512 + kv * 8) = y0;
      *(short8*)(kbuf + tb + (size_t)(8 + c8) * 512 + kv * 8) = y1;
    }
  } else {
    // ---- V: chunk-coalesced tile write (attn PV reads = 1 KB coalesced)
    const int kvh = ((n0 - 2560) >> 7) + hh;
    const int bb = m0 >> 11;
    const int kt0 = (m0 & (S_LEN - 1)) >> 6;
    const int kv0 = c8 * 8;
#pragma unroll
    for (int j = 0; j < 4; ++j) {
      int d = rid + 32 * j;            // 0..127 within head
#pragma unroll
      for (int half = 0; half < 4; ++half) {
        short8 vv = *(const short8*)&lds2[(hh * 128 + d) * 256 + half * 64 + kv0];
        size_t tb = ((size_t)(bb * 4 + kvh) * 32 + kt0 + half) * 8192;
        *(short8*)(vbuf + tb + ((c8 >> 2) * 8 + (d >> 4)) * 512
                        + ((c8 & 3) * 16 + (d & 15)) * 8) = vv;
      }
    }
  }
}

// --------------------------------------------------------------- AO GEMM
__global__ __launch_bounds__(512, 2) void gemm_bt_f32_kernel(
    const __hip_bfloat16* __restrict__ A,
    const __hip_bfloat16* __restrict__ Bt,
    float* __restrict__ C, int N, int K) {
  __shared__ __align__(16) __hip_bfloat16 lds[49152];  // 96 KiB
  const int tid = threadIdx.x;
  const int m0 = blockIdx.y * 256, n0 = blockIdx.x * 128;

  floatx4 acc[4][4] = {};
  gemm_256x128_core(A + (size_t)m0 * K, Bt + (size_t)n0 * K, K, lds, acc);

  const int wave = tid >> 6, lane = tid & 63;
  const int quad = lane >> 4, l15 = lane & 15;
  const int wm = wave >> 1, wn = wave & 1;
#pragma unroll
  for (int mi = 0; mi < 4; ++mi)
#pragma unroll
    for (int ni = 0; ni < 4; ++ni)
#pragma unroll
      for (int r = 0; r < 4; ++r) {
        int row = m0 + wm * 64 + mi * 16 + quad * 4 + r;
        int col = n0 + wn * 64 + ni * 16 + l15;
        C[(size_t)row * N + col] = acc[mi][ni][r];
      }
}

// ---------------------------------------------------------------- attention
// v4: round-2 structure (128 q-rows, 2 rowsets/wave, balanced pairing) with
// KVBLK=128: half the barriers / DMA drains / shfl chains / defer-max checks
// per kv. K: LDS dbuf 2x32 KB (DMA). V: NO LDS — chunk-coalesced 1 KB global
// loads (L2), batch 0 issued right after QK so latency hides under softmax,
// then va/vb ping-pong through the PV unroll (all statically indexed).
__global__ __launch_bounds__(256, 2) void attn_kernel(
    const __hip_bfloat16* __restrict__ qbuf,   // [4096][2048]
    const __hip_bfloat16* __restrict__ kbuf,   // 64-kv chunk tiles
    const __hip_bfloat16* __restrict__ vbuf,   // 64-kv chunk-coalesced tiles
    __hip_bfloat16* __restrict__ aout) {       // [4096][2048]
  const int qt = (blockIdx.y & 16) ? blockIdx.x : (15 - blockIdx.x);  // 0..15
  const int bh = blockIdx.y;
  const int b = bh >> 4, h = bh & 15;
  const int kvh = h >> 2;

  __shared__ __align__(16) __hip_bfloat16 Kbuf[2][16384];     // 2 x 32 KB

  const int tid = threadIdx.x;
  const int wave = tid >> 6, lane = tid & 63;
  const int quad = lane >> 4, l15 = lane & 15;

  short8 qfrag[2][4];
#pragma unroll
  for (int rs = 0; rs < 2; ++rs)
#pragma unroll
    for (int kc = 0; kc < 4; ++kc)
      qfrag[rs][kc] = *(const short8*)(qbuf +
          (size_t)(b * S_LEN + qt * 128 + rs * 64 + wave * 16 + l15) * 2048 +
          h * 128 + kc * 32 + quad * 8);

  const __hip_bfloat16* ktiles = kbuf + (size_t)(b * 4 + kvh) * 32 * 8192;
  const __hip_bfloat16* vtiles = vbuf + (size_t)(b * 4 + kvh) * 32 * 8192;
  const int nt = qt + 1;   // 128-kv tiles

  auto SK = [&](int t) {   // stage 64-kv tiles 2t, 2t+1 (32 KB contiguous)
#pragma unroll
    for (int j = 0; j < 8; ++j) {
      int c = tid + 256 * j;           // 0..2047 16B chunks
      gl_lds16(ktiles + (size_t)(2 * t) * 8192 + c * 8, &Kbuf[t & 1][c * 8]);
    }
  };

  SK(0);

  float m_s[2] = {-1e30f, -1e30f};
  float l_s[2] = {0.f, 0.f};
  floatx4 o[2][8] = {};

  for (int i = 0; i < nt; ++i) {
    __syncthreads();                 // K(i) DMA drained & visible
    if (i + 1 < nt) SK(i + 1);       // prefetch next K tile pair

    // S' = K Q^T: sc[rs][ni][r] = S[kv = i*128+ni*16+quad*4+r][q = l15]
    floatx4 sc[2][8] = {};
#pragma unroll
    for (int ni = 0; ni < 8; ++ni)
#pragma unroll
      for (int kc = 0; kc < 4; ++kc) {
        short8 bf = *(const short8*)&Kbuf[i & 1][
            (ni >> 2) * 8192 + ((kc * 4 + quad) * 64 + (ni & 3) * 16 + l15) * 8];
        sc[0][ni] = __builtin_amdgcn_mfma_f32_16x16x32_bf16(bf, qfrag[0][kc], sc[0][ni], 0, 0, 0);
        sc[1][ni] = __builtin_amdgcn_mfma_f32_16x16x32_bf16(bf, qfrag[1][kc], sc[1][ni], 0, 0, 0);
      }

    // early V batch 0 (kk2=0): latency hides under softmax
    const __hip_bfloat16* vt = vtiles + (size_t)(2 * i) * 8192;
    const int vl = quad * 16 + l15;
    short8 va[8], vb[8];
#pragma unroll
    for (int nc = 0; nc < 8; ++nc)
      va[nc] = *(const short8*)&vt[(nc * 64 + vl) * 8];

    const bool diag = (i == qt);
    short8 pa[2][4];
#pragma unroll
    for (int rs = 0; rs < 2; ++rs) {
      if (diag) {   // causal mask (rs0's upper half goes fully -1e30 -> p=0)
        const int qg = qt * 128 + rs * 64 + wave * 16 + l15;
#pragma unroll
        for (int ni = 0; ni < 8; ++ni) {
          int kvb = i * 128 + ni * 16 + quad * 4;
#pragma unroll
          for (int r = 0; r < 4; ++r)
            if (kvb + r > qg) sc[rs][ni][r] = -1e30f;
        }
      }

      // per-lane row max over this tile's 128 kv
      float v = sc[rs][0][0];
#pragma unroll
      for (int ni = 0; ni < 8; ++ni)
#pragma unroll
        for (int r = 0; r < 4; ++r) v = fmaxf(v, sc[rs][ni][r]);
      v = fmaxf(v, __shfl_xor(v, 16));
      v = fmaxf(v, __shfl_xor(v, 32));

      float mold = m_s[rs];
      if (__any(v > mold + THRR)) {    // defer-max: rescale only when needed
        float mnew = fmaxf(mold, v);
        float alpha = exp2f((mold - mnew) * CP);
        m_s[rs] = mnew;
        l_s[rs] *= alpha;
        float ar[4];
#pragma unroll
        for (int r = 0; r < 4; ++r)
          ar[r] = __shfl(alpha, (lane & 48) + quad * 4 + r);
#pragma unroll
        for (int nc = 0; nc < 8; ++nc)
#pragma unroll
          for (int r = 0; r < 4; ++r) o[rs][nc][r] *= ar[r];
      }

      float mc = m_s[rs] * CP;
      unsigned pk[8][2];
      float lsum = 0.f;
#pragma unroll
      for (int ni = 0; ni < 8; ++ni)
#pragma unroll
        for (int pr = 0; pr < 2; ++pr) {
          float p0 = exp2f(sc[rs][ni][2 * pr] * CP - mc);
          float p1 = exp2f(sc[rs][ni][2 * pr + 1] * CP - mc);
          lsum += p0 + p1;
          union { unsigned u; ushort us[2]; } uu;
          union { __hip_bfloat16 h; ushort us; } b0, b1;
          b0.h = __float2bfloat16(p0); b1.h = __float2bfloat16(p1);
          uu.us[0] = b0.us; uu.us[1] = b1.us;
          pk[ni][pr] = uu.u;
        }
      lsum += __shfl_xor(lsum, 16);
      lsum += __shfl_xor(lsum, 32);
      l_s[rs] += lsum;

      // quad-redistribution: pk[ni][pr]@lane(qs,l15) -> A-frag P[q=l15][kv]
#pragma unroll
      for (int kk2 = 0; kk2 < 4; ++kk2) {
        union { unsigned w[4]; short8 s; } pw_;
#pragma unroll
        for (int j = 0; j < 4; ++j) {
          int src = ((((quad & 1) * 2) + (j >> 1)) << 4) | l15;
          unsigned lo = (unsigned)__shfl((int)pk[2 * kk2][j & 1], src);
          unsigned hi = (unsigned)__shfl((int)pk[2 * kk2 + 1][j & 1], src);
          pw_.w[j] = (quad >> 1) ? hi : lo;
        }
        pa[rs][kk2] = pw_.s;
      }
    }

    // PV: va/vb ping-pong, next batch issued before current MFMAs
    __builtin_amdgcn_s_setprio(1);
#pragma unroll
    for (int nc = 0; nc < 8; ++nc)
      vb[nc] = *(const short8*)&vt[((8 + nc) * 64 + vl) * 8];          // kk2=1
#pragma unroll
    for (int nc = 0; nc < 8; ++nc) {
      o[0][nc] = __builtin_amdgcn_mfma_f32_16x16x32_bf16(pa[0][0], va[nc], o[0][nc], 0, 0, 0);
      o[1][nc] = __builtin_amdgcn_mfma_f32_16x16x32_bf16(pa[1][0], va[nc], o[1][nc], 0, 0, 0);
    }
#pragma unroll
    for (int nc = 0; nc < 8; ++nc)
      va[nc] = *(const short8*)&vt[8192 + (nc * 64 + vl) * 8];         // kk2=2
#pragma unroll
    for (int nc = 0; nc < 8; ++nc) {
      o[0][nc] = __builtin_amdgcn_mfma_f32_16x16x32_bf16(pa[0][1], vb[nc], o[0][nc], 0, 0, 0);
      o[1][nc] = __builtin_amdgcn_mfma_f32_16x16x32_bf16(pa[1][1], vb[nc], o[1][nc], 0, 0, 0);
    }
#pragma unroll
    for (int nc = 0; nc < 8; ++nc)
      vb[nc] = *(const short8*)&vt[8192 + ((8 + nc) * 64 + vl) * 8];   // kk2=3
#pragma unroll
    for (int nc = 0; nc < 8; ++nc) {
      o[0][nc] = __builtin_amdgcn_mfma_f32_16x16x32_bf16(pa[0][2], va[nc], o[0][nc], 0, 0, 0);
      o[1][nc] = __builtin_amdgcn_mfma_f32_16x16x32_bf16(pa[1][2], va[nc], o[1][nc], 0, 0, 0);
    }
#pragma unroll
    for (int nc = 0; nc < 8; ++nc) {
      o[0][nc] = __builtin_amdgcn_mfma_f32_16x16x32_bf16(pa[0][3], vb[nc], o[0][nc], 0, 0, 0);
      o[1][nc] = __builtin_amdgcn_mfma_f32_16x16x32_bf16(pa[1][3], vb[nc], o[1][nc], 0, 0, 0);
    }
    __builtin_amdgcn_s_setprio(0);
  }

#pragma unroll
  for (int rs = 0; rs < 2; ++rs) {
    float inv[4];
#pragma unroll
    for (int r = 0; r < 4; ++r) {
      float lr = __shfl(l_s[rs], (lane & 48) + quad * 4 + r);
      inv[r] = 1.0f / lr;
    }
    const size_t orow0 = (size_t)(b * S_LEN + qt * 128 + rs * 64 + wave * 16 + quad * 4);
#pragma unroll
    for (int nc = 0; nc < 8; ++nc)
#pragma unroll
      for (int r = 0; r < 4; ++r)
        aout[(orow0 + r) * 2048 + h * 128 + nc * 16 + l15] =
            __float2bfloat16(o[rs][nc][r] * inv[r]);
  }
}

// -------------------------------------------------------------------- launch
extern "C" void kernel_launch(void* const* d_in, const int* in_sizes, int n_in,
                              void* d_out, int out_size, void* d_ws, size_t ws_size,
                              hipStream_t stream) {
  const float* x    = (const float*)d_in[0];
  const float* cosb = (const float*)d_in[1];
  const float* sinb = (const float*)d_in[2];
  // d_in[3] = mask (causal, analytic)
  const float* Wq = (const float*)d_in[4];
  const float* Wk = (const float*)d_in[5];
  const float* Wv = (const float*)d_in[6];
  const float* Wo = (const float*)d_in[7];
  float* out = (float*)d_out;

  char* ws = (char*)d_ws;
  __hip_bfloat16* xb    = (__hip_bfloat16*)(ws);                 // 16 MB
  __hip_bfloat16* wqkvt = (__hip_bfloat16*)(ws + (16u << 20));   // 12 MB [3072][2048]
  __hip_bfloat16* wot   = (__hip_bfloat16*)(ws + (28u << 20));   // 8 MB  [2048][2048]
  __hip_bfloat16* qbuf  = (__hip_bfloat16*)(ws + (36u << 20));   // 16 MB [4096][2048]
  __hip_bfloat16* kbuf  = (__hip_bfloat16*)(ws + (52u << 20));   // 4 MB  tiles
  __hip_bfloat16* vbuf  = (__hip_bfloat16*)(ws + (56u << 20));   // 4 MB  tiles
  __hip_bfloat16* aout  = (__hip_bfloat16*)(ws + (60u << 20));   // 16 MB [4096][2048]

  prep_kernel<<<18432, 256, 0, stream>>>(x, Wq, Wk, Wv, Wo, xb, wqkvt, wot);
  qkv_gemm_kernel<<<dim3(12, 16), 512, 0, stream>>>(xb, wqkvt, qbuf, kbuf, vbuf, cosb, sinb);
  attn_kernel<<<dim3(16, 32), 256, 0, stream>>>(qbuf, kbuf, vbuf, aout);
  gemm_bt_f32_kernel<<<dim3(16, 16), 512, 0, stream>>>(aout, wot, out, 2048, 2048);
}

// Round 7
// 385.523 us; speedup vs baseline: 1.0342x; 1.0342x over previous
//
#include <hip/hip_runtime.h>
#include <hip/hip_bf16.h>
#include <cstdint>
#include <type_traits>

typedef __attribute__((ext_vector_type(8))) short short8;
typedef __attribute__((ext_vector_type(4))) float floatx4;

constexpr int S_LEN = 2048;
constexpr float ATTN_SCALE = 0.08838834764831845f;  // 128^-0.5
constexpr float LOG2E = 1.4426950408889634f;
constexpr float CP = ATTN_SCALE * LOG2E;            // fold scale into exp2 arg
constexpr float THRR = 5.0f / CP;                   // defer-max threshold (raw units)

// ---------------------------------------------------------------- async G->LDS
__device__ __forceinline__ void gl_lds16(const void* gp, void* lp) {
  __builtin_amdgcn_global_load_lds(
      (__attribute__((address_space(1))) void*)(uintptr_t)gp,
      (__attribute__((address_space(3))) void*)lp,
      16, 0, 0);
}

// --------------------------------------------------------------------- RoPE
__device__ __forceinline__ void rope8(short8 x0, short8 x1, const float* ca,
                                      const float* sa, const float* cb,
                                      const float* sb, short8& y0, short8& y1) {
#pragma unroll
  for (int e = 0; e < 8; ++e) {
    union { short s; __hip_bfloat16 h; } u0, u1, w0, w1;
    u0.s = x0[e]; u1.s = x1[e];
    float f0 = __bfloat162float(u0.h), f1 = __bfloat162float(u1.h);
    int j = e >> 1;
    w0.h = __float2bfloat16(f0 * ca[j] - f1 * sa[j]);
    w1.h = __float2bfloat16(f1 * cb[j] + f0 * sb[j]);
    y0[e] = w0.s; y1[e] = w1.s;
  }
}

// ------------------------------------------------------------- fused prologue
__device__ __forceinline__ void tr32(const float* __restrict__ src,
                                     __hip_bfloat16* __restrict__ dst,
                                     int blk, int nblk_x, int N, int tid,
                                     float (*tile)[33]) {
  int n0 = (blk % nblk_x) * 32, k0 = (blk / nblk_x) * 32;
  int tx = tid & 31, ty = tid >> 5;   // (32, 8)
#pragma unroll
  for (int i = ty; i < 32; i += 8)
    tile[i][tx] = src[(size_t)(k0 + i) * N + n0 + tx];
  __syncthreads();
#pragma unroll
  for (int i = ty; i < 32; i += 8)
    dst[(size_t)(n0 + i) * 2048 + k0 + tx] = __float2bfloat16(tile[tx][i]);
}

__global__ void prep_kernel(const float* __restrict__ x,
                            const float* __restrict__ Wq,
                            const float* __restrict__ Wk,
                            const float* __restrict__ Wv,
                            const float* __restrict__ Wo,
                            __hip_bfloat16* __restrict__ xb,
                            __hip_bfloat16* __restrict__ wqkvt,
                            __hip_bfloat16* __restrict__ wot) {
  __shared__ float tile[32][33];
  int bx = blockIdx.x, tid = threadIdx.x;
  if (bx < 8192) {
    int i = bx * 256 + tid;           // 2097152 float4s exactly
    float4 f = reinterpret_cast<const float4*>(x)[i];
    union { unsigned long long u64; __hip_bfloat16 h[4]; } u;
    u.h[0] = __float2bfloat16(f.x);
    u.h[1] = __float2bfloat16(f.y);
    u.h[2] = __float2bfloat16(f.z);
    u.h[3] = __float2bfloat16(f.w);
    reinterpret_cast<unsigned long long*>(xb)[i] = u.u64;
  } else if (bx < 12288) {
    tr32(Wq, wqkvt, bx - 8192, 64, 2048, tid, tile);
  } else if (bx < 13312) {
    tr32(Wk, wqkvt + 2048 * 2048, bx - 12288, 16, 512, tid, tile);
  } else if (bx < 14336) {
    tr32(Wv, wqkvt + 2560 * 2048, bx - 13312, 16, 512, tid, tile);
  } else {
    tr32(Wo, wot, bx - 14336, 64, 2048, tid, tile);
  }
}

// ===================================================================
// 256x256-tile 8-phase GEMM core (unchanged, proven). BK=64, 8 waves (2Mx4N),
// 128 KiB dbuf LDS, counted vmcnt(4), setprio around MFMA clusters.
// ===================================================================
__device__ __forceinline__ void gemm256_core(
    const __hip_bfloat16* __restrict__ Ab,   // A + m0*K, row-major [.][K]
    const __hip_bfloat16* __restrict__ Bb,   // Bt + n0*K, row-major [.][K]
    const int K, __hip_bfloat16* lds, floatx4 (&acc)[8][4]) {
  const int tid = threadIdx.x;
  const int wave = tid >> 6, lane = tid & 63;
  const int quad = lane >> 4, l15 = lane & 15;
  const int wm = wave >> 2, wn = wave & 3;
  const int nt = K >> 6;
  const int u2 = wave * 2;

  auto stA = [&](int tt, int h) {
    __hip_bfloat16* dst = lds + (tt & 1) * 32768;
    const int k0 = tt << 6;
#pragma unroll
    for (int j = 0; j < 2; ++j) {
      const int kc = (u2 + j) >> 1, rb = (u2 + j) & 1;
      gl_lds16(Ab + (size_t)(h * 128 + rb * 64 + lane) * K + k0 + kc * 8,
               dst + (kc * 256 + h * 128 + rb * 64) * 8);
    }
  };
  auto stB = [&](int tt, int h) {
    __hip_bfloat16* dst = lds + (tt & 1) * 32768 + 16384;
    const int k0 = tt << 6;
#pragma unroll
    for (int j = 0; j < 2; ++j) {
      const int kc = (u2 + j) >> 1, rb = (u2 + j) & 1;
      gl_lds16(Bb + (size_t)(h * 128 + rb * 64 + lane) * K + k0 + kc * 8,
               dst + (kc * 256 + h * 128 + rb * 64) * 8);
    }
  };

  // prologue: tile0 fully + tile1 B halves (A1 staged in tile0 ph0/ph1)
  stA(0, 0); stA(0, 1); stB(0, 0); stB(0, 1);
  if (nt > 1) { stB(1, 0); stB(1, 1); }
  asm volatile("s_waitcnt vmcnt(4)" ::: "memory");   // tile0's 8 loads landed
  __builtin_amdgcn_s_barrier();

  const int abase = (quad * 256 + wm * 128 + l15) * 8;
  const int bbase = (quad * 256 + wn * 64 + l15) * 8;

#pragma unroll 2
  for (int t = 0; t < nt; ++t) {
    const __hip_bfloat16* Al = lds + (t & 1) * 32768;
    const __hip_bfloat16* Bl = Al + 16384;
    short8 b[2][4];
#pragma unroll
    for (int q = 0; q < 4; ++q) {
      short8 a[2][2];
#pragma unroll
      for (int kk = 0; kk < 2; ++kk) {
        if (q == 0) {
#pragma unroll
          for (int ni = 0; ni < 4; ++ni)
            b[kk][ni] = *(const short8*)&Bl[kk * 8192 + bbase + ni * 128];
        }
#pragma unroll
        for (int mi = 0; mi < 2; ++mi)
          a[kk][mi] = *(const short8*)&Al[kk * 8192 + abase + (2 * q + mi) * 128];
      }
      if (q == 0)      { if (t + 1 < nt) stA(t + 1, 0); }
      else if (q == 1) { if (t + 1 < nt) stA(t + 1, 1); }
      else if (q == 2) { if (t + 2 < nt) stB(t + 2, 0); }
      else             { if (t + 2 < nt) stB(t + 2, 1); }
      __builtin_amdgcn_s_barrier();
      asm volatile("s_waitcnt lgkmcnt(0)" ::: "memory");
      __builtin_amdgcn_sched_barrier(0);    // rule #18: pin reads above MFMAs
      __builtin_amdgcn_s_setprio(1);
#pragma unroll
      for (int kk = 0; kk < 2; ++kk)
#pragma unroll
        for (int mi = 0; mi < 2; ++mi)
#pragma unroll
          for (int ni = 0; ni < 4; ++ni)
            acc[2 * q + mi][ni] = __builtin_amdgcn_mfma_f32_16x16x32_bf16(
                a[kk][mi], b[kk][ni], acc[2 * q + mi][ni], 0, 0, 0);
      __builtin_amdgcn_s_setprio(0);
      if (q == 3) {
        if (t + 2 < nt) asm volatile("s_waitcnt vmcnt(4)" ::: "memory");
        else            asm volatile("s_waitcnt vmcnt(0)" ::: "memory");
      }
      __builtin_amdgcn_s_barrier();
    }
  }
  asm volatile("" ::: "memory");   // fence before LDS reuse in epilogue
}

// ===================================================================
// 256x128-tile 2-phase GEMM core (unchanged, proven).
// ===================================================================
__device__ __forceinline__ void gemm_256x128_core(
    const __hip_bfloat16* __restrict__ Ab,
    const __hip_bfloat16* __restrict__ Bb,
    const int K, __hip_bfloat16* lds, floatx4 (&acc)[4][4]) {
  const int tid = threadIdx.x;
  const int wave = tid >> 6, lane = tid & 63;
  const int quad = lane >> 4, l15 = lane & 15;
  const int wm = wave >> 1, wn = wave & 1;
  const int nt = K >> 6;

  auto stA = [&](int tt, int c) {     // c in 0..3
    __hip_bfloat16* dst = lds + (tt & 1) * 24576;
    const int k0 = tt << 6;
    const int i = c * 8 + wave;       // 0..31: kc = i>>2, rowblk = i&3
    const int kc = i >> 2, rb = i & 3;
    gl_lds16(Ab + (size_t)(rb * 64 + lane) * K + k0 + kc * 8,
             dst + (kc * 256 + rb * 64) * 8);
  };
  auto stB = [&](int tt, int c) {     // c in 0..1
    __hip_bfloat16* dst = lds + (tt & 1) * 24576 + 16384;
    const int k0 = tt << 6;
    const int i = c * 8 + wave;       // 0..15: kc = i>>1, rowblk = i&1
    const int kc = i >> 1, rb = i & 1;
    gl_lds16(Bb + (size_t)(rb * 64 + lane) * K + k0 + kc * 8,
             dst + (kc * 128 + rb * 64) * 8);
  };

  stA(0, 0); stA(0, 1); stA(0, 2); stA(0, 3);
  stB(0, 0); stB(0, 1);
  if (nt > 1) {
    stB(1, 0); stB(1, 1);
    asm volatile("s_waitcnt vmcnt(2)" ::: "memory");
  } else {
    asm volatile("s_waitcnt vmcnt(0)" ::: "memory");
  }
  __builtin_amdgcn_s_barrier();

  const int abase = (quad * 256 + wm * 64 + l15) * 8;
  const int bbase = (quad * 128 + wn * 64 + l15) * 8;

#pragma unroll 2
  for (int t = 0; t < nt; ++t) {
    const __hip_bfloat16* Al = lds + (t & 1) * 24576;
    const __hip_bfloat16* Bl = Al + 16384;
    short8 b[2][4], a[2][2];
    // ---- phase 0: mi 0,1 (B frags read once per tile, reused in ph1)
#pragma unroll
    for (int kk = 0; kk < 2; ++kk) {
#pragma unroll
      for (int ni = 0; ni < 4; ++ni)
        b[kk][ni] = *(const short8*)&Bl[kk * 4096 + bbase + ni * 128];
#pragma unroll
      for (int mi = 0; mi < 2; ++mi)
        a[kk][mi] = *(const short8*)&Al[kk * 8192 + abase + mi * 128];
    }
    if (t + 1 < nt) { stA(t + 1, 0); stA(t + 1, 1); }
    __builtin_amdgcn_s_barrier();
    asm volatile("s_waitcnt lgkmcnt(0)" ::: "memory");
    __builtin_amdgcn_sched_barrier(0);
    __builtin_amdgcn_s_setprio(1);
#pragma unroll
    for (int kk = 0; kk < 2; ++kk)
#pragma unroll
      for (int mi = 0; mi < 2; ++mi)
#pragma unroll
        for (int ni = 0; ni < 4; ++ni)
          acc[mi][ni] = __builtin_amdgcn_mfma_f32_16x16x32_bf16(
              a[kk][mi], b[kk][ni], acc[mi][ni], 0, 0, 0);
    __builtin_amdgcn_s_setprio(0);
    __builtin_amdgcn_s_barrier();
    // ---- phase 1: mi 2,3
#pragma unroll
    for (int kk = 0; kk < 2; ++kk)
#pragma unroll
      for (int mi = 0; mi < 2; ++mi)
        a[kk][mi] = *(const short8*)&Al[kk * 8192 + abase + (2 + mi) * 128];
    if (t + 1 < nt) { stA(t + 1, 2); stA(t + 1, 3); }
    if (t + 2 < nt) { stB(t + 2, 0); stB(t + 2, 1); }
    __builtin_amdgcn_s_barrier();
    asm volatile("s_waitcnt lgkmcnt(0)" ::: "memory");
    __builtin_amdgcn_sched_barrier(0);
    __builtin_amdgcn_s_setprio(1);
#pragma unroll
    for (int kk = 0; kk < 2; ++kk)
#pragma unroll
      for (int mi = 0; mi < 2; ++mi)
#pragma unroll
        for (int ni = 0; ni < 4; ++ni)
          acc[2 + mi][ni] = __builtin_amdgcn_mfma_f32_16x16x32_bf16(
              a[kk][mi], b[kk][ni], acc[2 + mi][ni], 0, 0, 0);
    __builtin_amdgcn_s_setprio(0);
    if (t + 2 < nt) asm volatile("s_waitcnt vmcnt(2)" ::: "memory");
    else            asm volatile("s_waitcnt vmcnt(0)" ::: "memory");
    __builtin_amdgcn_s_barrier();
  }
  asm volatile("" ::: "memory");
}

// ------------------------------------------------------------ QKV GEMM (fused)
__global__ __launch_bounds__(512, 2) void qkv_gemm_kernel(
    const __hip_bfloat16* __restrict__ A,
    const __hip_bfloat16* __restrict__ Bt,
    __hip_bfloat16* __restrict__ qbuf,
    __hip_bfloat16* __restrict__ kbuf,
    __hip_bfloat16* __restrict__ vbuf,
    const float* __restrict__ cosb,
    const float* __restrict__ sinb) {
  constexpr int K = 2048;
  __shared__ __align__(16) __hip_bfloat16 lds[65536];  // 128 KiB
  const int tid = threadIdx.x;
  const int m0 = blockIdx.y * 256, n0 = blockIdx.x * 256;

  floatx4 acc[8][4] = {};
  gemm256_core(A + (size_t)m0 * K, Bt + (size_t)n0 * K, K, lds, acc);

  const int wave = tid >> 6, lane = tid & 63;
  const int quad = lane >> 4, l15 = lane & 15;
  const int wm = wave >> 2, wn = wave & 3;
  const bool isv = (n0 >= 2560);
  short* lds2 = (short*)lds;                       // [256][256] bf16 = 128 KB
#pragma unroll
  for (int mi = 0; mi < 8; ++mi)
#pragma unroll
    for (int ni = 0; ni < 4; ++ni)
#pragma unroll
      for (int r = 0; r < 4; ++r) {
        int row = wm * 128 + mi * 16 + quad * 4 + r;  // C/D: row = quad*4+reg
        int col = wn * 64 + ni * 16 + l15;            //      col = lane&15
        union { short s; __hip_bfloat16 h; } u;
        u.h = __float2bfloat16(acc[mi][ni][r]);
        if (isv) lds2[col * 256 + row] = u.s;         // V stored transposed
        else     lds2[row * 256 + col] = u.s;
      }
  __syncthreads();

  const int c16 = tid & 15, hh = c16 >> 3, c8 = c16 & 7;
  const int rid = tid >> 4, d0 = c8 * 8;
  if (n0 < 2048) {
    // ---- Q: rope + row-major coalesced write (2 heads per tile)
#pragma unroll
    for (int j = 0; j < 8; ++j) {
      int rr = rid + 32 * j;
      int rowg = m0 + rr;
      int s = rowg & (S_LEN - 1);
      float ca[4], sa[4], cb[4], sb[4];
      *(float4*)ca = *(const float4*)&cosb[s * 64 + c8 * 4];
      *(float4*)sa = *(const float4*)&sinb[s * 64 + c8 * 4];
      *(float4*)cb = *(const float4*)&cosb[s * 64 + 32 + c8 * 4];
      *(float4*)sb = *(const float4*)&sinb[s * 64 + 32 + c8 * 4];
      short8 x0 = *(const short8*)&lds2[rr * 256 + hh * 128 + d0];
      short8 x1 = *(const short8*)&lds2[rr * 256 + hh * 128 + 64 + d0];
      short8 y0, y1;
      rope8(x0, x1, ca, sa, cb, sb, y0, y1);
      *(short8*)(qbuf + (size_t)rowg * 2048 + n0 + hh * 128 + d0) = y0;
      *(short8*)(qbuf + (size_t)rowg * 2048 + n0 + hh * 128 + 64 + d0) = y1;
    }
  } else if (!isv) {
    // ---- K: rope + chunk-transposed tile write (2 kv-heads per tile)
    const int kvh = ((n0 - 2048) >> 7) + hh;
#pragma unroll
    for (int j = 0; j < 8; ++j) {
      int rr = rid + 32 * j;
      int rowg = m0 + rr;
      int s = rowg & (S_LEN - 1), bb = rowg >> 11;
      int kv = s & 63;
      size_t tb = ((size_t)(bb * 4 + kvh) * 32 + (s >> 6)) * 8192;
      float ca[4], sa[4], cb[4], sb[4];
      *(float4*)ca = *(const float4*)&cosb[s * 64 + c8 * 4];
      *(float4*)sa = *(const float4*)&sinb[s * 64 + c8 * 4];
      *(float4*)cb = *(const float4*)&cosb[s * 64 + 32 + c8 * 4];
      *(float4*)sb = *(const float4*)&sinb[s * 64 + 32 + c8 * 4];
      short8 x0 = *(const short8*)&lds2[rr * 256 + hh * 128 + d0];
      short8 x1 = *(const short8*)&lds2[rr * 256 + hh * 128 + 64 + d0];
      short8 y0, y1;
      rope8(x0, x1, ca, sa, cb, sb, y0, y1);
      *(short8*)(kbuf + tb + (size_t)c8 * 512 + kv * 8) = y0;
      *(short8*)(kbuf + tb + (size_t)(8 + c8) * 512 + kv * 8) = y1;
    }
  } else {
    // ---- V: transposed XOR-swizzled tile write (round-2 layout, matches attn)
    const int kvh = ((n0 - 2560) >> 7) + hh;
    const int bb = m0 >> 11;
    const int kt0 = (m0 & (S_LEN - 1)) >> 6;
    const int kv0 = c8 * 8;
#pragma unroll
    for (int j = 0; j < 4; ++j) {
      int d = rid + 32 * j;            // 0..127 within head
      int cxor = (d & 7) << 3;
#pragma unroll
      for (int half = 0; half < 4; ++half) {
        short8 vv = *(const short8*)&lds2[(hh * 128 + d) * 256 + half * 64 + kv0];
        size_t tb = ((size_t)(bb * 4 + kvh) * 32 + kt0 + half) * 8192;
        *(short8*)(vbuf + tb + d * 64 + (kv0 ^ cxor)) = vv;
      }
    }
  }
}

// --------------------------------------------------------------- AO GEMM
__global__ __launch_bounds__(512, 2) void gemm_bt_f32_kernel(
    const __hip_bfloat16* __restrict__ A,
    const __hip_bfloat16* __restrict__ Bt,
    float* __restrict__ C, int N, int K) {
  __shared__ __align__(16) __hip_bfloat16 lds[49152];  // 96 KiB
  const int tid = threadIdx.x;
  const int m0 = blockIdx.y * 256, n0 = blockIdx.x * 128;

  floatx4 acc[4][4] = {};
  gemm_256x128_core(A + (size_t)m0 * K, Bt + (size_t)n0 * K, K, lds, acc);

  const int wave = tid >> 6, lane = tid & 63;
  const int quad = lane >> 4, l15 = lane & 15;
  const int wm = wave >> 1, wn = wave & 1;
#pragma unroll
  for (int mi = 0; mi < 4; ++mi)
#pragma unroll
    for (int ni = 0; ni < 4; ++ni)
#pragma unroll
      for (int r = 0; r < 4; ++r) {
        int row = m0 + wm * 64 + mi * 16 + quad * 4 + r;
        int col = n0 + wn * 64 + ni * 16 + l15;
        C[(size_t)row * N + col] = acc[mi][ni][r];
      }
}

// ---------------------------------------------------------------- attention
// Round-2 structure (proven 94 us) with SAME-WORK CU PAIRING: qt = blockIdx.x
// unconditionally, so the two blocks co-resident on a CU (ids c and c+256:
// (bh, qt) and (bh+16, qt)) have IDENTICAL work and both stay resident the
// full makespan (2 waves/SIMD throughout). The old flip paired work 16 with
// work 1 -> CU ran half-empty 15/16 of the time (measured 13.3% occupancy).
__global__ __launch_bounds__(256, 2) void attn_kernel(
    const __hip_bfloat16* __restrict__ qbuf,   // [4096][2048]
    const __hip_bfloat16* __restrict__ kbuf,   // tiles
    const __hip_bfloat16* __restrict__ vbuf,   // tiles
    __hip_bfloat16* __restrict__ aout) {       // [4096][2048]
  const int qt = blockIdx.x;                   // same-work pairing (see above)
  const int bh = blockIdx.y;
  const int b = bh >> 4, h = bh & 15;
  const int kvh = h >> 2;

  __shared__ __align__(16) __hip_bfloat16 Kbuf[2][8192];      // 2 x 16 KB
  __shared__ __align__(16) __hip_bfloat16 Vbuf[2][8192];      // 2 x 16 KB

  const int tid = threadIdx.x;
  const int wave = tid >> 6, lane = tid & 63;
  const int quad = lane >> 4, l15 = lane & 15;

  short8 qfrag[2][4];
#pragma unroll
  for (int rs = 0; rs < 2; ++rs)
#pragma unroll
    for (int kc = 0; kc < 4; ++kc)
      qfrag[rs][kc] = *(const short8*)(qbuf +
          (size_t)(b * S_LEN + qt * 128 + rs * 64 + wave * 16 + l15) * 2048 +
          h * 128 + kc * 32 + quad * 8);

  const __hip_bfloat16* ktiles = kbuf + (size_t)(b * 4 + kvh) * 32 * 8192;
  const __hip_bfloat16* vtiles = vbuf + (size_t)(b * 4 + kvh) * 32 * 8192;
  const int nt = 2 * qt + 2;

#pragma unroll
  for (int j = 0; j < 4; ++j) {
    int c = tid + 256 * j;
    gl_lds16(ktiles + c * 8, &Kbuf[0][c * 8]);
    gl_lds16(vtiles + c * 8, &Vbuf[0][c * 8]);
  }

  float m_s[2] = {-1e30f, -1e30f};
  float l_s[2] = {0.f, 0.f};
  floatx4 o[2][8] = {};

  for (int kt = 0; kt < nt; ++kt) {
    const int cur = kt & 1;
    __syncthreads();   // K(kt)/V(kt) DMA drained & visible

    if (kt + 1 < nt) {
      const __hip_bfloat16* kb = ktiles + (size_t)(kt + 1) * 8192;
      const __hip_bfloat16* vb = vtiles + (size_t)(kt + 1) * 8192;
#pragma unroll
      for (int j = 0; j < 4; ++j) {
        int c = tid + 256 * j;
        gl_lds16(kb + c * 8, &Kbuf[1 - cur][c * 8]);
        gl_lds16(vb + c * 8, &Vbuf[1 - cur][c * 8]);
      }
    }

    // S' = K Q^T (swapped): sc[rs][ni][r] = S[kv=kt*64+ni*16+quad*4+r][q=l15]
    floatx4 sc[2][4] = {};
#pragma unroll
    for (int ni = 0; ni < 4; ++ni)
#pragma unroll
      for (int kc = 0; kc < 4; ++kc) {
        short8 bf = *(const short8*)&Kbuf[cur][((kc * 4 + quad) * 64 + ni * 16 + l15) * 8];
        sc[0][ni] = __builtin_amdgcn_mfma_f32_16x16x32_bf16(bf, qfrag[0][kc], sc[0][ni], 0, 0, 0);
        sc[1][ni] = __builtin_amdgcn_mfma_f32_16x16x32_bf16(bf, qfrag[1][kc], sc[1][ni], 0, 0, 0);
      }

    short8 pa[2][2];
#pragma unroll
    for (int rs = 0; rs < 2; ++rs) {
      const int qt64 = 2 * qt + rs;
      if (kt >= qt64) {   // diagonal or beyond: causal mask
        const int qg = qt * 128 + rs * 64 + wave * 16 + l15;
#pragma unroll
        for (int ni = 0; ni < 4; ++ni) {
          int kvb = kt * 64 + ni * 16 + quad * 4;
#pragma unroll
          for (int r = 0; r < 4; ++r)
            if (kvb + r > qg) sc[rs][ni][r] = -1e30f;
        }
      }

      // per-lane row max over this tile's 64 kv
      float v = sc[rs][0][0];
#pragma unroll
      for (int ni = 0; ni < 4; ++ni)
#pragma unroll
        for (int r = 0; r < 4; ++r) v = fmaxf(v, sc[rs][ni][r]);
      v = fmaxf(v, __shfl_xor(v, 16));
      v = fmaxf(v, __shfl_xor(v, 32));

      float mold = m_s[rs];
      if (__any(v > mold + THRR)) {      // defer-max: rescale only when needed
        float mnew = fmaxf(mold, v);
        float alpha = exp2f((mold - mnew) * CP);
        m_s[rs] = mnew;
        l_s[rs] *= alpha;
        float ar[4];
#pragma unroll
        for (int r = 0; r < 4; ++r)
          ar[r] = __shfl(alpha, (lane & 48) + quad * 4 + r);
#pragma unroll
        for (int nc = 0; nc < 8; ++nc)
#pragma unroll
          for (int r = 0; r < 4; ++r) o[rs][nc][r] *= ar[r];
      }

      float mc = m_s[rs] * CP;
      unsigned pk[4][2];
      float lsum = 0.f;
#pragma unroll
      for (int ni = 0; ni < 4; ++ni)
#pragma unroll
        for (int pr = 0; pr < 2; ++pr) {
          float p0 = exp2f(sc[rs][ni][2 * pr] * CP - mc);
          float p1 = exp2f(sc[rs][ni][2 * pr + 1] * CP - mc);
          lsum += p0 + p1;
          union { unsigned u; ushort us[2]; } uu;
          union { __hip_bfloat16 h; ushort us; } b0, b1;
          b0.h = __float2bfloat16(p0); b1.h = __float2bfloat16(p1);
          uu.us[0] = b0.us; uu.us[1] = b1.us;
          pk[ni][pr] = uu.u;
        }
      lsum += __shfl_xor(lsum, 16);
      lsum += __shfl_xor(lsum, 32);
      l_s[rs] += lsum;

      // quad-redistribution: pk[ni][pr]@lane(qs,l15) -> A-frag P[q=l15][kv]
#pragma unroll
      for (int kk2 = 0; kk2 < 2; ++kk2) {
        union { unsigned w[4]; short8 s; } pw_;
#pragma unroll
        for (int j = 0; j < 4; ++j) {
          int src = ((((quad & 1) * 2) + (j >> 1)) << 4) | l15;
          unsigned lo = (unsigned)__shfl((int)pk[2 * kk2][j & 1], src);
          unsigned hi = (unsigned)__shfl((int)pk[2 * kk2 + 1][j & 1], src);
          pw_.w[j] = (quad >> 1) ? hi : lo;
        }
        pa[rs][kk2] = pw_.s;
      }
    }

    // fused PV: each V fragment loaded once, used by both rowsets
    __builtin_amdgcn_s_setprio(1);
#pragma unroll
    for (int kk2 = 0; kk2 < 2; ++kk2) {
#pragma unroll
      for (int nc = 0; nc < 8; ++nc) {
        int d = nc * 16 + l15;
        int swcol = (kk2 * 32 + quad * 8) ^ ((d & 7) << 3);
        short8 vv = *(const short8*)&Vbuf[cur][d * 64 + swcol];
        o[0][nc] = __builtin_amdgcn_mfma_f32_16x16x32_bf16(pa[0][kk2], vv, o[0][nc], 0, 0, 0);
        o[1][nc] = __builtin_amdgcn_mfma_f32_16x16x32_bf16(pa[1][kk2], vv, o[1][nc], 0, 0, 0);
      }
    }
    __builtin_amdgcn_s_setprio(0);
  }

#pragma unroll
  for (int rs = 0; rs < 2; ++rs) {
    float inv[4];
#pragma unroll
    for (int r = 0; r < 4; ++r) {
      float lr = __shfl(l_s[rs], (lane & 48) + quad * 4 + r);
      inv[r] = 1.0f / lr;
    }
    const size_t orow0 = (size_t)(b * S_LEN + qt * 128 + rs * 64 + wave * 16 + quad * 4);
#pragma unroll
    for (int nc = 0; nc < 8; ++nc)
#pragma unroll
      for (int r = 0; r < 4; ++r)
        aout[(orow0 + r) * 2048 + h * 128 + nc * 16 + l15] =
            __float2bfloat16(o[rs][nc][r] * inv[r]);
  }
}

// -------------------------------------------------------------------- launch
extern "C" void kernel_launch(void* const* d_in, const int* in_sizes, int n_in,
                              void* d_out, int out_size, void* d_ws, size_t ws_size,
                              hipStream_t stream) {
  const float* x    = (const float*)d_in[0];
  const float* cosb = (const float*)d_in[1];
  const float* sinb = (const float*)d_in[2];
  // d_in[3] = mask (causal, analytic)
  const float* Wq = (const float*)d_in[4];
  const float* Wk = (const float*)d_in[5];
  const float* Wv = (const float*)d_in[6];
  const float* Wo = (const float*)d_in[7];
  float* out = (float*)d_out;

  char* ws = (char*)d_ws;
  __hip_bfloat16* xb    = (__hip_bfloat16*)(ws);                 // 16 MB
  __hip_bfloat16* wqkvt = (__hip_bfloat16*)(ws + (16u << 20));   // 12 MB [3072][2048]
  __hip_bfloat16* wot   = (__hip_bfloat16*)(ws + (28u << 20));   // 8 MB  [2048][2048]
  __hip_bfloat16* qbuf  = (__hip_bfloat16*)(ws + (36u << 20));   // 16 MB [4096][2048]
  __hip_bfloat16* kbuf  = (__hip_bfloat16*)(ws + (52u << 20));   // 4 MB  tiles
  __hip_bfloat16* vbuf  = (__hip_bfloat16*)(ws + (56u << 20));   // 4 MB  tiles
  __hip_bfloat16* aout  = (__hip_bfloat16*)(ws + (60u << 20));   // 16 MB [4096][2048]

  prep_kernel<<<18432, 256, 0, stream>>>(x, Wq, Wk, Wv, Wo, xb, wqkvt, wot);
  qkv_gemm_kernel<<<dim3(12, 16), 512, 0, stream>>>(xb, wqkvt, qbuf, kbuf, vbuf, cosb, sinb);
  attn_kernel<<<dim3(16, 32), 256, 0, stream>>>(qbuf, kbuf, vbuf, aout);
  gemm_bt_f32_kernel<<<dim3(16, 16), 512, 0, stream>>>(aout, wot, out, 2048, 2048);
}

// Round 8
// 359.161 us; speedup vs baseline: 1.1101x; 1.0734x over previous
//
#include <hip/hip_runtime.h>
#include <hip/hip_bf16.h>
#include <cstdint>
#include <type_traits>

typedef __attribute__((ext_vector_type(8))) short short8;
typedef __attribute__((ext_vector_type(4))) float floatx4;

constexpr int S_LEN = 2048;
constexpr float ATTN_SCALE = 0.08838834764831845f;  // 128^-0.5
constexpr float LOG2E = 1.4426950408889634f;
constexpr float CP = ATTN_SCALE * LOG2E;            // fold scale into exp2 arg
constexpr float THRR = 5.0f / CP;                   // defer-max threshold (raw units)

// ---------------------------------------------------------------- async G->LDS
__device__ __forceinline__ void gl_lds16(const void* gp, void* lp) {
  __builtin_amdgcn_global_load_lds(
      (__attribute__((address_space(1))) void*)(uintptr_t)gp,
      (__attribute__((address_space(3))) void*)lp,
      16, 0, 0);
}

// --------------------------------------------------------------------- RoPE
__device__ __forceinline__ void rope8(short8 x0, short8 x1, const float* ca,
                                      const float* sa, const float* cb,
                                      const float* sb, short8& y0, short8& y1) {
#pragma unroll
  for (int e = 0; e < 8; ++e) {
    union { short s; __hip_bfloat16 h; } u0, u1, w0, w1;
    u0.s = x0[e]; u1.s = x1[e];
    float f0 = __bfloat162float(u0.h), f1 = __bfloat162float(u1.h);
    int j = e >> 1;
    w0.h = __float2bfloat16(f0 * ca[j] - f1 * sa[j]);
    w1.h = __float2bfloat16(f1 * cb[j] + f0 * sb[j]);
    y0[e] = w0.s; y1[e] = w1.s;
  }
}

// ------------------------------------------------------------- fused prologue
__device__ __forceinline__ void tr32(const float* __restrict__ src,
                                     __hip_bfloat16* __restrict__ dst,
                                     int blk, int nblk_x, int N, int tid,
                                     float (*tile)[33]) {
  int n0 = (blk % nblk_x) * 32, k0 = (blk / nblk_x) * 32;
  int tx = tid & 31, ty = tid >> 5;   // (32, 8)
#pragma unroll
  for (int i = ty; i < 32; i += 8)
    tile[i][tx] = src[(size_t)(k0 + i) * N + n0 + tx];
  __syncthreads();
#pragma unroll
  for (int i = ty; i < 32; i += 8)
    dst[(size_t)(n0 + i) * 2048 + k0 + tx] = __float2bfloat16(tile[tx][i]);
}

__global__ void prep_kernel(const float* __restrict__ x,
                            const float* __restrict__ Wq,
                            const float* __restrict__ Wk,
                            const float* __restrict__ Wv,
                            const float* __restrict__ Wo,
                            __hip_bfloat16* __restrict__ xb,
                            __hip_bfloat16* __restrict__ wqkvt,
                            __hip_bfloat16* __restrict__ wot) {
  __shared__ float tile[32][33];
  int bx = blockIdx.x, tid = threadIdx.x;
  if (bx < 8192) {
    int i = bx * 256 + tid;           // 2097152 float4s exactly
    float4 f = reinterpret_cast<const float4*>(x)[i];
    union { unsigned long long u64; __hip_bfloat16 h[4]; } u;
    u.h[0] = __float2bfloat16(f.x);
    u.h[1] = __float2bfloat16(f.y);
    u.h[2] = __float2bfloat16(f.z);
    u.h[3] = __float2bfloat16(f.w);
    reinterpret_cast<unsigned long long*>(xb)[i] = u.u64;
  } else if (bx < 12288) {
    tr32(Wq, wqkvt, bx - 8192, 64, 2048, tid, tile);
  } else if (bx < 13312) {
    tr32(Wk, wqkvt + 2048 * 2048, bx - 12288, 16, 512, tid, tile);
  } else if (bx < 14336) {
    tr32(Wv, wqkvt + 2560 * 2048, bx - 13312, 16, 512, tid, tile);
  } else {
    tr32(Wo, wot, bx - 14336, 64, 2048, tid, tile);
  }
}

// ===================================================================
// 256x256-tile 8-phase GEMM core (unchanged, proven). BK=64, 8 waves (2Mx4N),
// 128 KiB dbuf LDS, counted vmcnt(4), setprio around MFMA clusters.
// ===================================================================
__device__ __forceinline__ void gemm256_core(
    const __hip_bfloat16* __restrict__ Ab,   // A + m0*K, row-major [.][K]
    const __hip_bfloat16* __restrict__ Bb,   // Bt + n0*K, row-major [.][K]
    const int K, __hip_bfloat16* lds, floatx4 (&acc)[8][4]) {
  const int tid = threadIdx.x;
  const int wave = tid >> 6, lane = tid & 63;
  const int quad = lane >> 4, l15 = lane & 15;
  const int wm = wave >> 2, wn = wave & 3;
  const int nt = K >> 6;
  const int u2 = wave * 2;

  auto stA = [&](int tt, int h) {
    __hip_bfloat16* dst = lds + (tt & 1) * 32768;
    const int k0 = tt << 6;
#pragma unroll
    for (int j = 0; j < 2; ++j) {
      const int kc = (u2 + j) >> 1, rb = (u2 + j) & 1;
      gl_lds16(Ab + (size_t)(h * 128 + rb * 64 + lane) * K + k0 + kc * 8,
               dst + (kc * 256 + h * 128 + rb * 64) * 8);
    }
  };
  auto stB = [&](int tt, int h) {
    __hip_bfloat16* dst = lds + (tt & 1) * 32768 + 16384;
    const int k0 = tt << 6;
#pragma unroll
    for (int j = 0; j < 2; ++j) {
      const int kc = (u2 + j) >> 1, rb = (u2 + j) & 1;
      gl_lds16(Bb + (size_t)(h * 128 + rb * 64 + lane) * K + k0 + kc * 8,
               dst + (kc * 256 + h * 128 + rb * 64) * 8);
    }
  };

  // prologue: tile0 fully + tile1 B halves (A1 staged in tile0 ph0/ph1)
  stA(0, 0); stA(0, 1); stB(0, 0); stB(0, 1);
  if (nt > 1) { stB(1, 0); stB(1, 1); }
  asm volatile("s_waitcnt vmcnt(4)" ::: "memory");   // tile0's 8 loads landed
  __builtin_amdgcn_s_barrier();

  const int abase = (quad * 256 + wm * 128 + l15) * 8;
  const int bbase = (quad * 256 + wn * 64 + l15) * 8;

#pragma unroll 2
  for (int t = 0; t < nt; ++t) {
    const __hip_bfloat16* Al = lds + (t & 1) * 32768;
    const __hip_bfloat16* Bl = Al + 16384;
    short8 b[2][4];
#pragma unroll
    for (int q = 0; q < 4; ++q) {
      short8 a[2][2];
#pragma unroll
      for (int kk = 0; kk < 2; ++kk) {
        if (q == 0) {
#pragma unroll
          for (int ni = 0; ni < 4; ++ni)
            b[kk][ni] = *(const short8*)&Bl[kk * 8192 + bbase + ni * 128];
        }
#pragma unroll
        for (int mi = 0; mi < 2; ++mi)
          a[kk][mi] = *(const short8*)&Al[kk * 8192 + abase + (2 * q + mi) * 128];
      }
      if (q == 0)      { if (t + 1 < nt) stA(t + 1, 0); }
      else if (q == 1) { if (t + 1 < nt) stA(t + 1, 1); }
      else if (q == 2) { if (t + 2 < nt) stB(t + 2, 0); }
      else             { if (t + 2 < nt) stB(t + 2, 1); }
      __builtin_amdgcn_s_barrier();
      asm volatile("s_waitcnt lgkmcnt(0)" ::: "memory");
      __builtin_amdgcn_sched_barrier(0);    // rule #18: pin reads above MFMAs
      __builtin_amdgcn_s_setprio(1);
#pragma unroll
      for (int kk = 0; kk < 2; ++kk)
#pragma unroll
        for (int mi = 0; mi < 2; ++mi)
#pragma unroll
          for (int ni = 0; ni < 4; ++ni)
            acc[2 * q + mi][ni] = __builtin_amdgcn_mfma_f32_16x16x32_bf16(
                a[kk][mi], b[kk][ni], acc[2 * q + mi][ni], 0, 0, 0);
      __builtin_amdgcn_s_setprio(0);
      if (q == 3) {
        if (t + 2 < nt) asm volatile("s_waitcnt vmcnt(4)" ::: "memory");
        else            asm volatile("s_waitcnt vmcnt(0)" ::: "memory");
      }
      __builtin_amdgcn_s_barrier();
    }
  }
  asm volatile("" ::: "memory");   // fence before LDS reuse in epilogue
}

// ===================================================================
// 256x128-tile 2-phase GEMM core (unchanged, proven).
// ===================================================================
__device__ __forceinline__ void gemm_256x128_core(
    const __hip_bfloat16* __restrict__ Ab,
    const __hip_bfloat16* __restrict__ Bb,
    const int K, __hip_bfloat16* lds, floatx4 (&acc)[4][4]) {
  const int tid = threadIdx.x;
  const int wave = tid >> 6, lane = tid & 63;
  const int quad = lane >> 4, l15 = lane & 15;
  const int wm = wave >> 1, wn = wave & 1;
  const int nt = K >> 6;

  auto stA = [&](int tt, int c) {     // c in 0..3
    __hip_bfloat16* dst = lds + (tt & 1) * 24576;
    const int k0 = tt << 6;
    const int i = c * 8 + wave;       // 0..31: kc = i>>2, rowblk = i&3
    const int kc = i >> 2, rb = i & 3;
    gl_lds16(Ab + (size_t)(rb * 64 + lane) * K + k0 + kc * 8,
             dst + (kc * 256 + rb * 64) * 8);
  };
  auto stB = [&](int tt, int c) {     // c in 0..1
    __hip_bfloat16* dst = lds + (tt & 1) * 24576 + 16384;
    const int k0 = tt << 6;
    const int i = c * 8 + wave;       // 0..15: kc = i>>1, rowblk = i&1
    const int kc = i >> 1, rb = i & 1;
    gl_lds16(Bb + (size_t)(rb * 64 + lane) * K + k0 + kc * 8,
             dst + (kc * 128 + rb * 64) * 8);
  };

  stA(0, 0); stA(0, 1); stA(0, 2); stA(0, 3);
  stB(0, 0); stB(0, 1);
  if (nt > 1) {
    stB(1, 0); stB(1, 1);
    asm volatile("s_waitcnt vmcnt(2)" ::: "memory");
  } else {
    asm volatile("s_waitcnt vmcnt(0)" ::: "memory");
  }
  __builtin_amdgcn_s_barrier();

  const int abase = (quad * 256 + wm * 64 + l15) * 8;
  const int bbase = (quad * 128 + wn * 64 + l15) * 8;

#pragma unroll 2
  for (int t = 0; t < nt; ++t) {
    const __hip_bfloat16* Al = lds + (t & 1) * 24576;
    const __hip_bfloat16* Bl = Al + 16384;
    short8 b[2][4], a[2][2];
    // ---- phase 0: mi 0,1 (B frags read once per tile, reused in ph1)
#pragma unroll
    for (int kk = 0; kk < 2; ++kk) {
#pragma unroll
      for (int ni = 0; ni < 4; ++ni)
        b[kk][ni] = *(const short8*)&Bl[kk * 4096 + bbase + ni * 128];
#pragma unroll
      for (int mi = 0; mi < 2; ++mi)
        a[kk][mi] = *(const short8*)&Al[kk * 8192 + abase + mi * 128];
    }
    if (t + 1 < nt) { stA(t + 1, 0); stA(t + 1, 1); }
    __builtin_amdgcn_s_barrier();
    asm volatile("s_waitcnt lgkmcnt(0)" ::: "memory");
    __builtin_amdgcn_sched_barrier(0);
    __builtin_amdgcn_s_setprio(1);
#pragma unroll
    for (int kk = 0; kk < 2; ++kk)
#pragma unroll
      for (int mi = 0; mi < 2; ++mi)
#pragma unroll
        for (int ni = 0; ni < 4; ++ni)
          acc[mi][ni] = __builtin_amdgcn_mfma_f32_16x16x32_bf16(
              a[kk][mi], b[kk][ni], acc[mi][ni], 0, 0, 0);
    __builtin_amdgcn_s_setprio(0);
    __builtin_amdgcn_s_barrier();
    // ---- phase 1: mi 2,3
#pragma unroll
    for (int kk = 0; kk < 2; ++kk)
#pragma unroll
      for (int mi = 0; mi < 2; ++mi)
        a[kk][mi] = *(const short8*)&Al[kk * 8192 + abase + (2 + mi) * 128];
    if (t + 1 < nt) { stA(t + 1, 2); stA(t + 1, 3); }
    if (t + 2 < nt) { stB(t + 2, 0); stB(t + 2, 1); }
    __builtin_amdgcn_s_barrier();
    asm volatile("s_waitcnt lgkmcnt(0)" ::: "memory");
    __builtin_amdgcn_sched_barrier(0);
    __builtin_amdgcn_s_setprio(1);
#pragma unroll
    for (int kk = 0; kk < 2; ++kk)
#pragma unroll
      for (int mi = 0; mi < 2; ++mi)
#pragma unroll
        for (int ni = 0; ni < 4; ++ni)
          acc[2 + mi][ni] = __builtin_amdgcn_mfma_f32_16x16x32_bf16(
              a[kk][mi], b[kk][ni], acc[2 + mi][ni], 0, 0, 0);
    __builtin_amdgcn_s_setprio(0);
    if (t + 2 < nt) asm volatile("s_waitcnt vmcnt(2)" ::: "memory");
    else            asm volatile("s_waitcnt vmcnt(0)" ::: "memory");
    __builtin_amdgcn_s_barrier();
  }
  asm volatile("" ::: "memory");
}

// ------------------------------------------------------------ QKV GEMM (fused)
__global__ __launch_bounds__(512, 2) void qkv_gemm_kernel(
    const __hip_bfloat16* __restrict__ A,
    const __hip_bfloat16* __restrict__ Bt,
    __hip_bfloat16* __restrict__ qbuf,
    __hip_bfloat16* __restrict__ kbuf,
    __hip_bfloat16* __restrict__ vbuf,
    const float* __restrict__ cosb,
    const float* __restrict__ sinb) {
  constexpr int K = 2048;
  __shared__ __align__(16) __hip_bfloat16 lds[65536];  // 128 KiB
  const int tid = threadIdx.x;
  const int m0 = blockIdx.y * 256, n0 = blockIdx.x * 256;

  floatx4 acc[8][4] = {};
  gemm256_core(A + (size_t)m0 * K, Bt + (size_t)n0 * K, K, lds, acc);

  const int wave = tid >> 6, lane = tid & 63;
  const int quad = lane >> 4, l15 = lane & 15;
  const int wm = wave >> 2, wn = wave & 3;
  const bool isv = (n0 >= 2560);
  short* lds2 = (short*)lds;                       // [256][256] bf16 = 128 KB
#pragma unroll
  for (int mi = 0; mi < 8; ++mi)
#pragma unroll
    for (int ni = 0; ni < 4; ++ni)
#pragma unroll
      for (int r = 0; r < 4; ++r) {
        int row = wm * 128 + mi * 16 + quad * 4 + r;  // C/D: row = quad*4+reg
        int col = wn * 64 + ni * 16 + l15;            //      col = lane&15
        union { short s; __hip_bfloat16 h; } u;
        u.h = __float2bfloat16(acc[mi][ni][r]);
        if (isv) lds2[col * 256 + row] = u.s;         // V stored transposed
        else     lds2[row * 256 + col] = u.s;
      }
  __syncthreads();

  const int c16 = tid & 15, hh = c16 >> 3, c8 = c16 & 7;
  const int rid = tid >> 4, d0 = c8 * 8;
  if (n0 < 2048) {
    // ---- Q: rope + row-major coalesced write (2 heads per tile)
#pragma unroll
    for (int j = 0; j < 8; ++j) {
      int rr = rid + 32 * j;
      int rowg = m0 + rr;
      int s = rowg & (S_LEN - 1);
      float ca[4], sa[4], cb[4], sb[4];
      *(float4*)ca = *(const float4*)&cosb[s * 64 + c8 * 4];
      *(float4*)sa = *(const float4*)&sinb[s * 64 + c8 * 4];
      *(float4*)cb = *(const float4*)&cosb[s * 64 + 32 + c8 * 4];
      *(float4*)sb = *(const float4*)&sinb[s * 64 + 32 + c8 * 4];
      short8 x0 = *(const short8*)&lds2[rr * 256 + hh * 128 + d0];
      short8 x1 = *(const short8*)&lds2[rr * 256 + hh * 128 + 64 + d0];
      short8 y0, y1;
      rope8(x0, x1, ca, sa, cb, sb, y0, y1);
      *(short8*)(qbuf + (size_t)rowg * 2048 + n0 + hh * 128 + d0) = y0;
      *(short8*)(qbuf + (size_t)rowg * 2048 + n0 + hh * 128 + 64 + d0) = y1;
    }
  } else if (!isv) {
    // ---- K: rope + chunk-transposed tile write (2 kv-heads per tile)
    const int kvh = ((n0 - 2048) >> 7) + hh;
#pragma unroll
    for (int j = 0; j < 8; ++j) {
      int rr = rid + 32 * j;
      int rowg = m0 + rr;
      int s = rowg & (S_LEN - 1), bb = rowg >> 11;
      int kv = s & 63;
      size_t tb = ((size_t)(bb * 4 + kvh) * 32 + (s >> 6)) * 8192;
      float ca[4], sa[4], cb[4], sb[4];
      *(float4*)ca = *(const float4*)&cosb[s * 64 + c8 * 4];
      *(float4*)sa = *(const float4*)&sinb[s * 64 + c8 * 4];
      *(float4*)cb = *(const float4*)&cosb[s * 64 + 32 + c8 * 4];
      *(float4*)sb = *(const float4*)&sinb[s * 64 + 32 + c8 * 4];
      short8 x0 = *(const short8*)&lds2[rr * 256 + hh * 128 + d0];
      short8 x1 = *(const short8*)&lds2[rr * 256 + hh * 128 + 64 + d0];
      short8 y0, y1;
      rope8(x0, x1, ca, sa, cb, sb, y0, y1);
      *(short8*)(kbuf + tb + (size_t)c8 * 512 + kv * 8) = y0;
      *(short8*)(kbuf + tb + (size_t)(8 + c8) * 512 + kv * 8) = y1;
    }
  } else {
    // ---- V: transposed XOR-swizzled tile write (matches attn PV reads)
    const int kvh = ((n0 - 2560) >> 7) + hh;
    const int bb = m0 >> 11;
    const int kt0 = (m0 & (S_LEN - 1)) >> 6;
    const int kv0 = c8 * 8;
#pragma unroll
    for (int j = 0; j < 4; ++j) {
      int d = rid + 32 * j;            // 0..127 within head
      int cxor = (d & 7) << 3;
#pragma unroll
      for (int half = 0; half < 4; ++half) {
        short8 vv = *(const short8*)&lds2[(hh * 128 + d) * 256 + half * 64 + kv0];
        size_t tb = ((size_t)(bb * 4 + kvh) * 32 + kt0 + half) * 8192;
        *(short8*)(vbuf + tb + d * 64 + (kv0 ^ cxor)) = vv;
      }
    }
  }
}

// --------------------------------------------------------------- AO GEMM
__global__ __launch_bounds__(512, 2) void gemm_bt_f32_kernel(
    const __hip_bfloat16* __restrict__ A,
    const __hip_bfloat16* __restrict__ Bt,
    float* __restrict__ C, int N, int K) {
  __shared__ __align__(16) __hip_bfloat16 lds[49152];  // 96 KiB
  const int tid = threadIdx.x;
  const int m0 = blockIdx.y * 256, n0 = blockIdx.x * 128;

  floatx4 acc[4][4] = {};
  gemm_256x128_core(A + (size_t)m0 * K, Bt + (size_t)n0 * K, K, lds, acc);

  const int wave = tid >> 6, lane = tid & 63;
  const int quad = lane >> 4, l15 = lane & 15;
  const int wm = wave >> 1, wn = wave & 1;
#pragma unroll
  for (int mi = 0; mi < 4; ++mi)
#pragma unroll
    for (int ni = 0; ni < 4; ++ni)
#pragma unroll
      for (int r = 0; r < 4; ++r) {
        int row = m0 + wm * 64 + mi * 16 + quad * 4 + r;
        int col = n0 + wn * 64 + ni * 16 + l15;
        C[(size_t)row * N + col] = acc[mi][ni][r];
      }
}

// ---------------------------------------------------------------- attention
// v6 DUAL-ENDED: each block owns TWO 64-row q-tiles from opposite ends of the
// causal triangle: rowset0 = q-tile j, rowset1 = q-tile 31-j (j = blockIdx.x).
// kv loop runs 0..31-j; rowset0 participates only while kt <= j. Per-block
// MFMA work = (j+1)+(32-j) = 33 tile-units for EVERY block -> any dispatch
// pairing is compute-balanced and co-resident blocks stay live the whole
// makespan (fixes both the flip's temporal imbalance and qt=bx's CU-total
// imbalance). Inner tile body = round-2's proven code verbatim.
__global__ __launch_bounds__(256, 2) void attn_kernel(
    const __hip_bfloat16* __restrict__ qbuf,   // [4096][2048]
    const __hip_bfloat16* __restrict__ kbuf,   // tiles
    const __hip_bfloat16* __restrict__ vbuf,   // tiles
    __hip_bfloat16* __restrict__ aout) {       // [4096][2048]
  const int j = blockIdx.x;                    // 0..15
  const int bh = blockIdx.y;
  const int b = bh >> 4, h = bh & 15;
  const int kvh = h >> 2;
  const int jq[2] = {j, 31 - j};               // 64-row q-tiles (both ends)

  __shared__ __align__(16) __hip_bfloat16 Kbuf[2][8192];      // 2 x 16 KB
  __shared__ __align__(16) __hip_bfloat16 Vbuf[2][8192];      // 2 x 16 KB

  const int tid = threadIdx.x;
  const int wave = tid >> 6, lane = tid & 63;
  const int quad = lane >> 4, l15 = lane & 15;

  short8 qfrag[2][4];
#pragma unroll
  for (int rs = 0; rs < 2; ++rs)
#pragma unroll
    for (int kc = 0; kc < 4; ++kc)
      qfrag[rs][kc] = *(const short8*)(qbuf +
          (size_t)(b * S_LEN + jq[rs] * 64 + wave * 16 + l15) * 2048 +
          h * 128 + kc * 32 + quad * 8);

  const __hip_bfloat16* ktiles = kbuf + (size_t)(b * 4 + kvh) * 32 * 8192;
  const __hip_bfloat16* vtiles = vbuf + (size_t)(b * 4 + kvh) * 32 * 8192;
  const int nt = 32 - j;   // rowset1 needs kv tiles 0..31-j

#pragma unroll
  for (int jj = 0; jj < 4; ++jj) {
    int c = tid + 256 * jj;
    gl_lds16(ktiles + c * 8, &Kbuf[0][c * 8]);
    gl_lds16(vtiles + c * 8, &Vbuf[0][c * 8]);
  }

  float m_s[2] = {-1e30f, -1e30f};
  float l_s[2] = {0.f, 0.f};
  floatx4 o[2][8] = {};

  for (int kt = 0; kt < nt; ++kt) {
    const int cur = kt & 1;
    __syncthreads();   // K(kt)/V(kt) DMA drained & visible

    if (kt + 1 < nt) {
      const __hip_bfloat16* kb = ktiles + (size_t)(kt + 1) * 8192;
      const __hip_bfloat16* vb = vtiles + (size_t)(kt + 1) * 8192;
#pragma unroll
      for (int jj = 0; jj < 4; ++jj) {
        int c = tid + 256 * jj;
        gl_lds16(kb + c * 8, &Kbuf[1 - cur][c * 8]);
        gl_lds16(vb + c * 8, &Vbuf[1 - cur][c * 8]);
      }
    }

    const bool do0 = (kt <= j);   // rowset0 fully masked beyond its diagonal

    // S' = K Q^T (swapped): sc[rs][ni][r] = S[kv=kt*64+ni*16+quad*4+r][q=l15]
    floatx4 sc[2][4] = {};
#pragma unroll
    for (int ni = 0; ni < 4; ++ni)
#pragma unroll
      for (int kc = 0; kc < 4; ++kc) {
        short8 bf = *(const short8*)&Kbuf[cur][((kc * 4 + quad) * 64 + ni * 16 + l15) * 8];
        if (do0)
          sc[0][ni] = __builtin_amdgcn_mfma_f32_16x16x32_bf16(bf, qfrag[0][kc], sc[0][ni], 0, 0, 0);
        sc[1][ni] = __builtin_amdgcn_mfma_f32_16x16x32_bf16(bf, qfrag[1][kc], sc[1][ni], 0, 0, 0);
      }

    short8 pa[2][2];
#pragma unroll
    for (int rs = 0; rs < 2; ++rs) {
      if (rs == 0 && !do0) continue;
      if (kt >= jq[rs]) {   // diagonal tile: causal mask
        const int qg = jq[rs] * 64 + wave * 16 + l15;
#pragma unroll
        for (int ni = 0; ni < 4; ++ni) {
          int kvb = kt * 64 + ni * 16 + quad * 4;
#pragma unroll
          for (int r = 0; r < 4; ++r)
            if (kvb + r > qg) sc[rs][ni][r] = -1e30f;
        }
      }

      // per-lane row max over this tile's 64 kv
      float v = sc[rs][0][0];
#pragma unroll
      for (int ni = 0; ni < 4; ++ni)
#pragma unroll
        for (int r = 0; r < 4; ++r) v = fmaxf(v, sc[rs][ni][r]);
      v = fmaxf(v, __shfl_xor(v, 16));
      v = fmaxf(v, __shfl_xor(v, 32));

      float mold = m_s[rs];
      if (__any(v > mold + THRR)) {      // defer-max: rescale only when needed
        float mnew = fmaxf(mold, v);
        float alpha = exp2f((mold - mnew) * CP);
        m_s[rs] = mnew;
        l_s[rs] *= alpha;
        float ar[4];
#pragma unroll
        for (int r = 0; r < 4; ++r)
          ar[r] = __shfl(alpha, (lane & 48) + quad * 4 + r);
#pragma unroll
        for (int nc = 0; nc < 8; ++nc)
#pragma unroll
          for (int r = 0; r < 4; ++r) o[rs][nc][r] *= ar[r];
      }

      float mc = m_s[rs] * CP;
      unsigned pk[4][2];
      float lsum = 0.f;
#pragma unroll
      for (int ni = 0; ni < 4; ++ni)
#pragma unroll
        for (int pr = 0; pr < 2; ++pr) {
          float p0 = exp2f(sc[rs][ni][2 * pr] * CP - mc);
          float p1 = exp2f(sc[rs][ni][2 * pr + 1] * CP - mc);
          lsum += p0 + p1;
          union { unsigned u; ushort us[2]; } uu;
          union { __hip_bfloat16 h; ushort us; } b0, b1;
          b0.h = __float2bfloat16(p0); b1.h = __float2bfloat16(p1);
          uu.us[0] = b0.us; uu.us[1] = b1.us;
          pk[ni][pr] = uu.u;
        }
      lsum += __shfl_xor(lsum, 16);
      lsum += __shfl_xor(lsum, 32);
      l_s[rs] += lsum;

      // quad-redistribution: pk[ni][pr]@lane(qs,l15) -> A-frag P[q=l15][kv]
#pragma unroll
      for (int kk2 = 0; kk2 < 2; ++kk2) {
        union { unsigned w[4]; short8 s; } pw_;
#pragma unroll
        for (int jj = 0; jj < 4; ++jj) {
          int src = ((((quad & 1) * 2) + (jj >> 1)) << 4) | l15;
          unsigned lo = (unsigned)__shfl((int)pk[2 * kk2][jj & 1], src);
          unsigned hi = (unsigned)__shfl((int)pk[2 * kk2 + 1][jj & 1], src);
          pw_.w[jj] = (quad >> 1) ? hi : lo;
        }
        pa[rs][kk2] = pw_.s;
      }
    }

    // fused PV: each V fragment loaded once, used by active rowsets
    __builtin_amdgcn_s_setprio(1);
#pragma unroll
    for (int kk2 = 0; kk2 < 2; ++kk2) {
#pragma unroll
      for (int nc = 0; nc < 8; ++nc) {
        int d = nc * 16 + l15;
        int swcol = (kk2 * 32 + quad * 8) ^ ((d & 7) << 3);
        short8 vv = *(const short8*)&Vbuf[cur][d * 64 + swcol];
        if (do0)
          o[0][nc] = __builtin_amdgcn_mfma_f32_16x16x32_bf16(pa[0][kk2], vv, o[0][nc], 0, 0, 0);
        o[1][nc] = __builtin_amdgcn_mfma_f32_16x16x32_bf16(pa[1][kk2], vv, o[1][nc], 0, 0, 0);
      }
    }
    __builtin_amdgcn_s_setprio(0);
  }

#pragma unroll
  for (int rs = 0; rs < 2; ++rs) {
    float inv[4];
#pragma unroll
    for (int r = 0; r < 4; ++r) {
      float lr = __shfl(l_s[rs], (lane & 48) + quad * 4 + r);
      inv[r] = 1.0f / lr;
    }
    const size_t orow0 = (size_t)(b * S_LEN + jq[rs] * 64 + wave * 16 + quad * 4);
#pragma unroll
    for (int nc = 0; nc < 8; ++nc)
#pragma unroll
      for (int r = 0; r < 4; ++r)
        aout[(orow0 + r) * 2048 + h * 128 + nc * 16 + l15] =
            __float2bfloat16(o[rs][nc][r] * inv[r]);
  }
}

// -------------------------------------------------------------------- launch
extern "C" void kernel_launch(void* const* d_in, const int* in_sizes, int n_in,
                              void* d_out, int out_size, void* d_ws, size_t ws_size,
                              hipStream_t stream) {
  const float* x    = (const float*)d_in[0];
  const float* cosb = (const float*)d_in[1];
  const float* sinb = (const float*)d_in[2];
  // d_in[3] = mask (causal, analytic)
  const float* Wq = (const float*)d_in[4];
  const float* Wk = (const float*)d_in[5];
  const float* Wv = (const float*)d_in[6];
  const float* Wo = (const float*)d_in[7];
  float* out = (float*)d_out;

  char* ws = (char*)d_ws;
  __hip_bfloat16* xb    = (__hip_bfloat16*)(ws);                 // 16 MB
  __hip_bfloat16* wqkvt = (__hip_bfloat16*)(ws + (16u << 20));   // 12 MB [3072][2048]
  __hip_bfloat16* wot   = (__hip_bfloat16*)(ws + (28u << 20));   // 8 MB  [2048][2048]
  __hip_bfloat16* qbuf  = (__hip_bfloat16*)(ws + (36u << 20));   // 16 MB [4096][2048]
  __hip_bfloat16* kbuf  = (__hip_bfloat16*)(ws + (52u << 20));   // 4 MB  tiles
  __hip_bfloat16* vbuf  = (__hip_bfloat16*)(ws + (56u << 20));   // 4 MB  tiles
  __hip_bfloat16* aout  = (__hip_bfloat16*)(ws + (60u << 20));   // 16 MB [4096][2048]

  prep_kernel<<<18432, 256, 0, stream>>>(x, Wq, Wk, Wv, Wo, xb, wqkvt, wot);
  qkv_gemm_kernel<<<dim3(12, 16), 512, 0, stream>>>(xb, wqkvt, qbuf, kbuf, vbuf, cosb, sinb);
  attn_kernel<<<dim3(16, 32), 256, 0, stream>>>(qbuf, kbuf, vbuf, aout);
  gemm_bt_f32_kernel<<<dim3(16, 16), 512, 0, stream>>>(aout, wot, out, 2048, 2048);
}

// Round 10
// 352.606 us; speedup vs baseline: 1.1307x; 1.0186x over previous
//
#include <hip/hip_runtime.h>
#include <hip/hip_bf16.h>
#include <cstdint>
#include <type_traits>

typedef __attribute__((ext_vector_type(8))) short short8;
typedef __attribute__((ext_vector_type(4))) float floatx4;

constexpr int S_LEN = 2048;
constexpr float ATTN_SCALE = 0.08838834764831845f;  // 128^-0.5
constexpr float LOG2E = 1.4426950408889634f;
constexpr float CP = ATTN_SCALE * LOG2E;            // fold scale into exp2 arg
constexpr float THRR = 5.0f / CP;                   // defer-max threshold (raw units)

// ---------------------------------------------------------------- async G->LDS
__device__ __forceinline__ void gl_lds16(const void* gp, void* lp) {
  __builtin_amdgcn_global_load_lds(
      (__attribute__((address_space(1))) void*)(uintptr_t)gp,
      (__attribute__((address_space(3))) void*)lp,
      16, 0, 0);
}

// --------------------------------------------------------------------- RoPE
__device__ __forceinline__ void rope8(short8 x0, short8 x1, const float* ca,
                                      const float* sa, const float* cb,
                                      const float* sb, short8& y0, short8& y1) {
#pragma unroll
  for (int e = 0; e < 8; ++e) {
    union { short s; __hip_bfloat16 h; } u0, u1, w0, w1;
    u0.s = x0[e]; u1.s = x1[e];
    float f0 = __bfloat162float(u0.h), f1 = __bfloat162float(u1.h);
    int j = e >> 1;
    w0.h = __float2bfloat16(f0 * ca[j] - f1 * sa[j]);
    w1.h = __float2bfloat16(f1 * cb[j] + f0 * sb[j]);
    y0[e] = w0.s; y1[e] = w1.s;
  }
}

// ------------------------------------------------------------- fused prologue
// 64(k) x 64(n) transpose tile: float4 256B row reads, LDS [64][65] (2-way
// bank aliasing only = free), FULL 128B line writes (32 lanes x short2 per
// n-row). Replaces tr32 whose 64B partial-line writes made prep ~2x slower.
__device__ __forceinline__ void tr64(const float* __restrict__ src,
                                     __hip_bfloat16* __restrict__ dst,
                                     int blk, int nblk_x, int N, int tid,
                                     float (*tile)[65]) {
  int n0 = (blk % nblk_x) * 64, k0 = (blk / nblk_x) * 64;
  int tx = tid & 15, ty = tid >> 4;          // (16, 16)
#pragma unroll
  for (int p = 0; p < 4; ++p) {
    int i = ty + p * 16;                     // k-row 0..63
    float4 f = *(const float4*)&src[(size_t)(k0 + i) * N + n0 + tx * 4];
    tile[i][tx * 4 + 0] = f.x;
    tile[i][tx * 4 + 1] = f.y;
    tile[i][tx * 4 + 2] = f.z;
    tile[i][tx * 4 + 3] = f.w;
  }
  __syncthreads();
  int wx = tid & 31, wy = tid >> 5;          // (32, 8)
#pragma unroll
  for (int p = 0; p < 8; ++p) {
    int n = wy + p * 8;                      // n-row 0..63
    union { unsigned u; ushort us[2]; } uu;
    union { __hip_bfloat16 h; ushort us; } h0, h1;
    h0.h = __float2bfloat16(tile[wx * 2 + 0][n]);
    h1.h = __float2bfloat16(tile[wx * 2 + 1][n]);
    uu.us[0] = h0.us; uu.us[1] = h1.us;
    *(unsigned*)&dst[(size_t)(n0 + n) * 2048 + k0 + wx * 2] = uu.u;
  }
}

// blocks [0,8192): x fp32 -> bf16; [8192,9216): Wq^T; [9216,9472): Wk^T;
// [9472,9728): Wv^T; [9728,10752): Wo^T   (64x64 tiles)
__global__ void prep_kernel(const float* __restrict__ x,
                            const float* __restrict__ Wq,
                            const float* __restrict__ Wk,
                            const float* __restrict__ Wv,
                            const float* __restrict__ Wo,
                            __hip_bfloat16* __restrict__ xb,
                            __hip_bfloat16* __restrict__ wqkvt,
                            __hip_bfloat16* __restrict__ wot) {
  __shared__ float tile[64][65];
  int bx = blockIdx.x, tid = threadIdx.x;
  if (bx < 8192) {
    int i = bx * 256 + tid;           // 2097152 float4s exactly
    float4 f = reinterpret_cast<const float4*>(x)[i];
    union { unsigned long long u64; __hip_bfloat16 h[4]; } u;
    u.h[0] = __float2bfloat16(f.x);
    u.h[1] = __float2bfloat16(f.y);
    u.h[2] = __float2bfloat16(f.z);
    u.h[3] = __float2bfloat16(f.w);
    reinterpret_cast<unsigned long long*>(xb)[i] = u.u64;
  } else if (bx < 9216) {
    tr64(Wq, wqkvt, bx - 8192, 32, 2048, tid, tile);
  } else if (bx < 9472) {
    tr64(Wk, wqkvt + 2048 * 2048, bx - 9216, 8, 512, tid, tile);
  } else if (bx < 9728) {
    tr64(Wv, wqkvt + 2560 * 2048, bx - 9472, 8, 512, tid, tile);
  } else {
    tr64(Wo, wot, bx - 9728, 32, 2048, tid, tile);
  }
}

// ===================================================================
// 256x256-tile 8-phase GEMM core (unchanged, proven). BK=64, 8 waves (2Mx4N),
// 128 KiB dbuf LDS, counted vmcnt(4), setprio around MFMA clusters.
// ===================================================================
__device__ __forceinline__ void gemm256_core(
    const __hip_bfloat16* __restrict__ Ab,   // A + m0*K, row-major [.][K]
    const __hip_bfloat16* __restrict__ Bb,   // Bt + n0*K, row-major [.][K]
    const int K, __hip_bfloat16* lds, floatx4 (&acc)[8][4]) {
  const int tid = threadIdx.x;
  const int wave = tid >> 6, lane = tid & 63;
  const int quad = lane >> 4, l15 = lane & 15;
  const int wm = wave >> 2, wn = wave & 3;
  const int nt = K >> 6;
  const int u2 = wave * 2;

  auto stA = [&](int tt, int h) {
    __hip_bfloat16* dst = lds + (tt & 1) * 32768;
    const int k0 = tt << 6;
#pragma unroll
    for (int j = 0; j < 2; ++j) {
      const int kc = (u2 + j) >> 1, rb = (u2 + j) & 1;
      gl_lds16(Ab + (size_t)(h * 128 + rb * 64 + lane) * K + k0 + kc * 8,
               dst + (kc * 256 + h * 128 + rb * 64) * 8);
    }
  };
  auto stB = [&](int tt, int h) {
    __hip_bfloat16* dst = lds + (tt & 1) * 32768 + 16384;
    const int k0 = tt << 6;
#pragma unroll
    for (int j = 0; j < 2; ++j) {
      const int kc = (u2 + j) >> 1, rb = (u2 + j) & 1;
      gl_lds16(Bb + (size_t)(h * 128 + rb * 64 + lane) * K + k0 + kc * 8,
               dst + (kc * 256 + h * 128 + rb * 64) * 8);
    }
  };

  // prologue: tile0 fully + tile1 B halves (A1 staged in tile0 ph0/ph1)
  stA(0, 0); stA(0, 1); stB(0, 0); stB(0, 1);
  if (nt > 1) { stB(1, 0); stB(1, 1); }
  asm volatile("s_waitcnt vmcnt(4)" ::: "memory");   // tile0's 8 loads landed
  __builtin_amdgcn_s_barrier();

  const int abase = (quad * 256 + wm * 128 + l15) * 8;
  const int bbase = (quad * 256 + wn * 64 + l15) * 8;

#pragma unroll 2
  for (int t = 0; t < nt; ++t) {
    const __hip_bfloat16* Al = lds + (t & 1) * 32768;
    const __hip_bfloat16* Bl = Al + 16384;
    short8 b[2][4];
#pragma unroll
    for (int q = 0; q < 4; ++q) {
      short8 a[2][2];
#pragma unroll
      for (int kk = 0; kk < 2; ++kk) {
        if (q == 0) {
#pragma unroll
          for (int ni = 0; ni < 4; ++ni)
            b[kk][ni] = *(const short8*)&Bl[kk * 8192 + bbase + ni * 128];
        }
#pragma unroll
        for (int mi = 0; mi < 2; ++mi)
          a[kk][mi] = *(const short8*)&Al[kk * 8192 + abase + (2 * q + mi) * 128];
      }
      if (q == 0)      { if (t + 1 < nt) stA(t + 1, 0); }
      else if (q == 1) { if (t + 1 < nt) stA(t + 1, 1); }
      else if (q == 2) { if (t + 2 < nt) stB(t + 2, 0); }
      else             { if (t + 2 < nt) stB(t + 2, 1); }
      __builtin_amdgcn_s_barrier();
      asm volatile("s_waitcnt lgkmcnt(0)" ::: "memory");
      __builtin_amdgcn_sched_barrier(0);    // rule #18: pin reads above MFMAs
      __builtin_amdgcn_s_setprio(1);
#pragma unroll
      for (int kk = 0; kk < 2; ++kk)
#pragma unroll
        for (int mi = 0; mi < 2; ++mi)
#pragma unroll
          for (int ni = 0; ni < 4; ++ni)
            acc[2 * q + mi][ni] = __builtin_amdgcn_mfma_f32_16x16x32_bf16(
                a[kk][mi], b[kk][ni], acc[2 * q + mi][ni], 0, 0, 0);
      __builtin_amdgcn_s_setprio(0);
      if (q == 3) {
        if (t + 2 < nt) asm volatile("s_waitcnt vmcnt(4)" ::: "memory");
        else            asm volatile("s_waitcnt vmcnt(0)" ::: "memory");
      }
      __builtin_amdgcn_s_barrier();
    }
  }
  asm volatile("" ::: "memory");   // fence before LDS reuse in epilogue
}

// ===================================================================
// 256x128-tile 2-phase GEMM core (unchanged, proven).
// ===================================================================
__device__ __forceinline__ void gemm_256x128_core(
    const __hip_bfloat16* __restrict__ Ab,
    const __hip_bfloat16* __restrict__ Bb,
    const int K, __hip_bfloat16* lds, floatx4 (&acc)[4][4]) {
  const int tid = threadIdx.x;
  const int wave = tid >> 6, lane = tid & 63;
  const int quad = lane >> 4, l15 = lane & 15;
  const int wm = wave >> 1, wn = wave & 1;
  const int nt = K >> 6;

  auto stA = [&](int tt, int c) {     // c in 0..3
    __hip_bfloat16* dst = lds + (tt & 1) * 24576;
    const int k0 = tt << 6;
    const int i = c * 8 + wave;       // 0..31: kc = i>>2, rowblk = i&3
    const int kc = i >> 2, rb = i & 3;
    gl_lds16(Ab + (size_t)(rb * 64 + lane) * K + k0 + kc * 8,
             dst + (kc * 256 + rb * 64) * 8);
  };
  auto stB = [&](int tt, int c) {     // c in 0..1
    __hip_bfloat16* dst = lds + (tt & 1) * 24576 + 16384;
    const int k0 = tt << 6;
    const int i = c * 8 + wave;       // 0..15: kc = i>>1, rowblk = i&1
    const int kc = i >> 1, rb = i & 1;
    gl_lds16(Bb + (size_t)(rb * 64 + lane) * K + k0 + kc * 8,
             dst + (kc * 128 + rb * 64) * 8);
  };

  stA(0, 0); stA(0, 1); stA(0, 2); stA(0, 3);
  stB(0, 0); stB(0, 1);
  if (nt > 1) {
    stB(1, 0); stB(1, 1);
    asm volatile("s_waitcnt vmcnt(2)" ::: "memory");
  } else {
    asm volatile("s_waitcnt vmcnt(0)" ::: "memory");
  }
  __builtin_amdgcn_s_barrier();

  const int abase = (quad * 256 + wm * 64 + l15) * 8;
  const int bbase = (quad * 128 + wn * 64 + l15) * 8;

#pragma unroll 2
  for (int t = 0; t < nt; ++t) {
    const __hip_bfloat16* Al = lds + (t & 1) * 24576;
    const __hip_bfloat16* Bl = Al + 16384;
    short8 b[2][4], a[2][2];
    // ---- phase 0: mi 0,1 (B frags read once per tile, reused in ph1)
#pragma unroll
    for (int kk = 0; kk < 2; ++kk) {
#pragma unroll
      for (int ni = 0; ni < 4; ++ni)
        b[kk][ni] = *(const short8*)&Bl[kk * 4096 + bbase + ni * 128];
#pragma unroll
      for (int mi = 0; mi < 2; ++mi)
        a[kk][mi] = *(const short8*)&Al[kk * 8192 + abase + mi * 128];
    }
    if (t + 1 < nt) { stA(t + 1, 0); stA(t + 1, 1); }
    __builtin_amdgcn_s_barrier();
    asm volatile("s_waitcnt lgkmcnt(0)" ::: "memory");
    __builtin_amdgcn_sched_barrier(0);
    __builtin_amdgcn_s_setprio(1);
#pragma unroll
    for (int kk = 0; kk < 2; ++kk)
#pragma unroll
      for (int mi = 0; mi < 2; ++mi)
#pragma unroll
        for (int ni = 0; ni < 4; ++ni)
          acc[mi][ni] = __builtin_amdgcn_mfma_f32_16x16x32_bf16(
              a[kk][mi], b[kk][ni], acc[mi][ni], 0, 0, 0);
    __builtin_amdgcn_s_setprio(0);
    __builtin_amdgcn_s_barrier();
    // ---- phase 1: mi 2,3
#pragma unroll
    for (int kk = 0; kk < 2; ++kk)
#pragma unroll
      for (int mi = 0; mi < 2; ++mi)
        a[kk][mi] = *(const short8*)&Al[kk * 8192 + abase + (2 + mi) * 128];
    if (t + 1 < nt) { stA(t + 1, 2); stA(t + 1, 3); }
    if (t + 2 < nt) { stB(t + 2, 0); stB(t + 2, 1); }
    __builtin_amdgcn_s_barrier();
    asm volatile("s_waitcnt lgkmcnt(0)" ::: "memory");
    __builtin_amdgcn_sched_barrier(0);
    __builtin_amdgcn_s_setprio(1);
#pragma unroll
    for (int kk = 0; kk < 2; ++kk)
#pragma unroll
      for (int mi = 0; mi < 2; ++mi)
#pragma unroll
        for (int ni = 0; ni < 4; ++ni)
          acc[2 + mi][ni] = __builtin_amdgcn_mfma_f32_16x16x32_bf16(
              a[kk][mi], b[kk][ni], acc[2 + mi][ni], 0, 0, 0);
    __builtin_amdgcn_s_setprio(0);
    if (t + 2 < nt) asm volatile("s_waitcnt vmcnt(2)" ::: "memory");
    else            asm volatile("s_waitcnt vmcnt(0)" ::: "memory");
    __builtin_amdgcn_s_barrier();
  }
  asm volatile("" ::: "memory");
}

// ------------------------------------------------------------ QKV GEMM (fused)
__global__ __launch_bounds__(512, 2) void qkv_gemm_kernel(
    const __hip_bfloat16* __restrict__ A,
    const __hip_bfloat16* __restrict__ Bt,
    __hip_bfloat16* __restrict__ qbuf,
    __hip_bfloat16* __restrict__ kbuf,
    __hip_bfloat16* __restrict__ vbuf,
    const float* __restrict__ cosb,
    const float* __restrict__ sinb) {
  constexpr int K = 2048;
  __shared__ __align__(16) __hip_bfloat16 lds[65536];  // 128 KiB
  const int tid = threadIdx.x;
  const int m0 = blockIdx.y * 256, n0 = blockIdx.x * 256;

  floatx4 acc[8][4] = {};
  gemm256_core(A + (size_t)m0 * K, Bt + (size_t)n0 * K, K, lds, acc);

  const int wave = tid >> 6, lane = tid & 63;
  const int quad = lane >> 4, l15 = lane & 15;
  const int wm = wave >> 2, wn = wave & 3;
  const bool isv = (n0 >= 2560);
  short* lds2 = (short*)lds;                       // [256][256] bf16 = 128 KB
#pragma unroll
  for (int mi = 0; mi < 8; ++mi)
#pragma unroll
    for (int ni = 0; ni < 4; ++ni)
#pragma unroll
      for (int r = 0; r < 4; ++r) {
        int row = wm * 128 + mi * 16 + quad * 4 + r;  // C/D: row = quad*4+reg
        int col = wn * 64 + ni * 16 + l15;            //      col = lane&15
        union { short s; __hip_bfloat16 h; } u;
        u.h = __float2bfloat16(acc[mi][ni][r]);
        if (isv) lds2[col * 256 + row] = u.s;         // V stored transposed
        else     lds2[row * 256 + col] = u.s;
      }
  __syncthreads();

  const int c16 = tid & 15, hh = c16 >> 3, c8 = c16 & 7;
  const int rid = tid >> 4, d0 = c8 * 8;
  if (n0 < 2048) {
    // ---- Q: rope + row-major coalesced write (2 heads per tile)
#pragma unroll
    for (int j = 0; j < 8; ++j) {
      int rr = rid + 32 * j;
      int rowg = m0 + rr;
      int s = rowg & (S_LEN - 1);
      float ca[4], sa[4], cb[4], sb[4];
      *(float4*)ca = *(const float4*)&cosb[s * 64 + c8 * 4];
      *(float4*)sa = *(const float4*)&sinb[s * 64 + c8 * 4];
      *(float4*)cb = *(const float4*)&cosb[s * 64 + 32 + c8 * 4];
      *(float4*)sb = *(const float4*)&sinb[s * 64 + 32 + c8 * 4];
      short8 x0 = *(const short8*)&lds2[rr * 256 + hh * 128 + d0];
      short8 x1 = *(const short8*)&lds2[rr * 256 + hh * 128 + 64 + d0];
      short8 y0, y1;
      rope8(x0, x1, ca, sa, cb, sb, y0, y1);
      *(short8*)(qbuf + (size_t)rowg * 2048 + n0 + hh * 128 + d0) = y0;
      *(short8*)(qbuf + (size_t)rowg * 2048 + n0 + hh * 128 + 64 + d0) = y1;
    }
  } else if (!isv) {
    // ---- K: rope + chunk-transposed tile write (2 kv-heads per tile)
    const int kvh = ((n0 - 2048) >> 7) + hh;
#pragma unroll
    for (int j = 0; j < 8; ++j) {
      int rr = rid + 32 * j;
      int rowg = m0 + rr;
      int s = rowg & (S_LEN - 1), bb = rowg >> 11;
      int kv = s & 63;
      size_t tb = ((size_t)(bb * 4 + kvh) * 32 + (s >> 6)) * 8192;
      float ca[4], sa[4], cb[4], sb[4];
      *(float4*)ca = *(const float4*)&cosb[s * 64 + c8 * 4];
      *(float4*)sa = *(const float4*)&sinb[s * 64 + c8 * 4];
      *(float4*)cb = *(const float4*)&cosb[s * 64 + 32 + c8 * 4];
      *(float4*)sb = *(const float4*)&sinb[s * 64 + 32 + c8 * 4];
      short8 x0 = *(const short8*)&lds2[rr * 256 + hh * 128 + d0];
      short8 x1 = *(const short8*)&lds2[rr * 256 + hh * 128 + 64 + d0];
      short8 y0, y1;
      rope8(x0, x1, ca, sa, cb, sb, y0, y1);
      *(short8*)(kbuf + tb + (size_t)c8 * 512 + kv * 8) = y0;
      *(short8*)(kbuf + tb + (size_t)(8 + c8) * 512 + kv * 8) = y1;
    }
  } else {
    // ---- V: transposed XOR-swizzled tile write (matches attn PV reads)
    const int kvh = ((n0 - 2560) >> 7) + hh;
    const int bb = m0 >> 11;
    const int kt0 = (m0 & (S_LEN - 1)) >> 6;
    const int kv0 = c8 * 8;
#pragma unroll
    for (int j = 0; j < 4; ++j) {
      int d = rid + 32 * j;            // 0..127 within head
      int cxor = (d & 7) << 3;
#pragma unroll
      for (int half = 0; half < 4; ++half) {
        short8 vv = *(const short8*)&lds2[(hh * 128 + d) * 256 + half * 64 + kv0];
        size_t tb = ((size_t)(bb * 4 + kvh) * 32 + kt0 + half) * 8192;
        *(short8*)(vbuf + tb + d * 64 + (kv0 ^ cxor)) = vv;
      }
    }
  }
}

// --------------------------------------------------------------- AO GEMM
__global__ __launch_bounds__(512, 2) void gemm_bt_f32_kernel(
    const __hip_bfloat16* __restrict__ A,
    const __hip_bfloat16* __restrict__ Bt,
    float* __restrict__ C, int N, int K) {
  __shared__ __align__(16) __hip_bfloat16 lds[49152];  // 96 KiB
  const int tid = threadIdx.x;
  const int m0 = blockIdx.y * 256, n0 = blockIdx.x * 128;

  floatx4 acc[4][4] = {};
  gemm_256x128_core(A + (size_t)m0 * K, Bt + (size_t)n0 * K, K, lds, acc);

  const int wave = tid >> 6, lane = tid & 63;
  const int quad = lane >> 4, l15 = lane & 15;
  const int wm = wave >> 1, wn = wave & 1;
#pragma unroll
  for (int mi = 0; mi < 4; ++mi)
#pragma unroll
    for (int ni = 0; ni < 4; ++ni)
#pragma unroll
      for (int r = 0; r < 4; ++r) {
        int row = m0 + wm * 64 + mi * 16 + quad * 4 + r;
        int col = n0 + wn * 64 + ni * 16 + l15;
        C[(size_t)row * N + col] = acc[mi][ni][r];
      }
}

// ---------------------------------------------------------------- attention
// v6 DUAL-ENDED (proven 87.8 us): rowset0 = q-tile j, rowset1 = q-tile 31-j;
// kv loop 0..31-j; per-block work = 33 tile-units for every block.
__global__ __launch_bounds__(256, 2) void attn_kernel(
    const __hip_bfloat16* __restrict__ qbuf,   // [4096][2048]
    const __hip_bfloat16* __restrict__ kbuf,   // tiles
    const __hip_bfloat16* __restrict__ vbuf,   // tiles
    __hip_bfloat16* __restrict__ aout) {       // [4096][2048]
  const int j = blockIdx.x;                    // 0..15
  const int bh = blockIdx.y;
  const int b = bh >> 4, h = bh & 15;
  const int kvh = h >> 2;
  const int jq[2] = {j, 31 - j};               // 64-row q-tiles (both ends)

  __shared__ __align__(16) __hip_bfloat16 Kbuf[2][8192];      // 2 x 16 KB
  __shared__ __align__(16) __hip_bfloat16 Vbuf[2][8192];      // 2 x 16 KB

  const int tid = threadIdx.x;
  const int wave = tid >> 6, lane = tid & 63;
  const int quad = lane >> 4, l15 = lane & 15;

  short8 qfrag[2][4];
#pragma unroll
  for (int rs = 0; rs < 2; ++rs)
#pragma unroll
    for (int kc = 0; kc < 4; ++kc)
      qfrag[rs][kc] = *(const short8*)(qbuf +
          (size_t)(b * S_LEN + jq[rs] * 64 + wave * 16 + l15) * 2048 +
          h * 128 + kc * 32 + quad * 8);

  const __hip_bfloat16* ktiles = kbuf + (size_t)(b * 4 + kvh) * 32 * 8192;
  const __hip_bfloat16* vtiles = vbuf + (size_t)(b * 4 + kvh) * 32 * 8192;
  const int nt = 32 - j;   // rowset1 needs kv tiles 0..31-j

#pragma unroll
  for (int jj = 0; jj < 4; ++jj) {
    int c = tid + 256 * jj;
    gl_lds16(ktiles + c * 8, &Kbuf[0][c * 8]);
    gl_lds16(vtiles + c * 8, &Vbuf[0][c * 8]);
  }

  float m_s[2] = {-1e30f, -1e30f};
  float l_s[2] = {0.f, 0.f};
  floatx4 o[2][8] = {};

  for (int kt = 0; kt < nt; ++kt) {
    const int cur = kt & 1;
    __syncthreads();   // K(kt)/V(kt) DMA drained & visible

    if (kt + 1 < nt) {
      const __hip_bfloat16* kb = ktiles + (size_t)(kt + 1) * 8192;
      const __hip_bfloat16* vb = vtiles + (size_t)(kt + 1) * 8192;
#pragma unroll
      for (int jj = 0; jj < 4; ++jj) {
        int c = tid + 256 * jj;
        gl_lds16(kb + c * 8, &Kbuf[1 - cur][c * 8]);
        gl_lds16(vb + c * 8, &Vbuf[1 - cur][c * 8]);
      }
    }

    const bool do0 = (kt <= j);   // rowset0 fully masked beyond its diagonal

    // S' = K Q^T (swapped): sc[rs][ni][r] = S[kv=kt*64+ni*16+quad*4+r][q=l15]
    floatx4 sc[2][4] = {};
#pragma unroll
    for (int ni = 0; ni < 4; ++ni)
#pragma unroll
      for (int kc = 0; kc < 4; ++kc) {
        short8 bf = *(const short8*)&Kbuf[cur][((kc * 4 + quad) * 64 + ni * 16 + l15) * 8];
        if (do0)
          sc[0][ni] = __builtin_amdgcn_mfma_f32_16x16x32_bf16(bf, qfrag[0][kc], sc[0][ni], 0, 0, 0);
        sc[1][ni] = __builtin_amdgcn_mfma_f32_16x16x32_bf16(bf, qfrag[1][kc], sc[1][ni], 0, 0, 0);
      }

    short8 pa[2][2];
#pragma unroll
    for (int rs = 0; rs < 2; ++rs) {
      if (rs == 0 && !do0) continue;
      if (kt >= jq[rs]) {   // diagonal tile: causal mask
        const int qg = jq[rs] * 64 + wave * 16 + l15;
#pragma unroll
        for (int ni = 0; ni < 4; ++ni) {
          int kvb = kt * 64 + ni * 16 + quad * 4;
#pragma unroll
          for (int r = 0; r < 4; ++r)
            if (kvb + r > qg) sc[rs][ni][r] = -1e30f;
        }
      }

      // per-lane row max over this tile's 64 kv
      float v = sc[rs][0][0];
#pragma unroll
      for (int ni = 0; ni < 4; ++ni)
#pragma unroll
        for (int r = 0; r < 4; ++r) v = fmaxf(v, sc[rs][ni][r]);
      v = fmaxf(v, __shfl_xor(v, 16));
      v = fmaxf(v, __shfl_xor(v, 32));

      float mold = m_s[rs];
      if (__any(v > mold + THRR)) {      // defer-max: rescale only when needed
        float mnew = fmaxf(mold, v);
        float alpha = exp2f((mold - mnew) * CP);
        m_s[rs] = mnew;
        l_s[rs] *= alpha;
        float ar[4];
#pragma unroll
        for (int r = 0; r < 4; ++r)
          ar[r] = __shfl(alpha, (lane & 48) + quad * 4 + r);
#pragma unroll
        for (int nc = 0; nc < 8; ++nc)
#pragma unroll
          for (int r = 0; r < 4; ++r) o[rs][nc][r] *= ar[r];
      }

      float mc = m_s[rs] * CP;
      unsigned pk[4][2];
      float lsum = 0.f;
#pragma unroll
      for (int ni = 0; ni < 4; ++ni)
#pragma unroll
        for (int pr = 0; pr < 2; ++pr) {
          float p0 = exp2f(sc[rs][ni][2 * pr] * CP - mc);
          float p1 = exp2f(sc[rs][ni][2 * pr + 1] * CP - mc);
          lsum += p0 + p1;
          union { unsigned u; ushort us[2]; } uu;
          union { __hip_bfloat16 h; ushort us; } b0, b1;
          b0.h = __float2bfloat16(p0); b1.h = __float2bfloat16(p1);
          uu.us[0] = b0.us; uu.us[1] = b1.us;
          pk[ni][pr] = uu.u;
        }
      lsum += __shfl_xor(lsum, 16);
      lsum += __shfl_xor(lsum, 32);
      l_s[rs] += lsum;

      // quad-redistribution: pk[ni][pr]@lane(qs,l15) -> A-frag P[q=l15][kv]
#pragma unroll
      for (int kk2 = 0; kk2 < 2; ++kk2) {
        union { unsigned w[4]; short8 s; } pw_;
#pragma unroll
        for (int jj = 0; jj < 4; ++jj) {
          int src = ((((quad & 1) * 2) + (jj >> 1)) << 4) | l15;
          unsigned lo = (unsigned)__shfl((int)pk[2 * kk2][jj & 1], src);
          unsigned hi = (unsigned)__shfl((int)pk[2 * kk2 + 1][jj & 1], src);
          pw_.w[jj] = (quad >> 1) ? hi : lo;
        }
        pa[rs][kk2] = pw_.s;
      }
    }

    // fused PV: each V fragment loaded once, used by active rowsets
    __builtin_amdgcn_s_setprio(1);
#pragma unroll
    for (int kk2 = 0; kk2 < 2; ++kk2) {
#pragma unroll
      for (int nc = 0; nc < 8; ++nc) {
        int d = nc * 16 + l15;
        int swcol = (kk2 * 32 + quad * 8) ^ ((d & 7) << 3);
        short8 vv = *(const short8*)&Vbuf[cur][d * 64 + swcol];
        if (do0)
          o[0][nc] = __builtin_amdgcn_mfma_f32_16x16x32_bf16(pa[0][kk2], vv, o[0][nc], 0, 0, 0);
        o[1][nc] = __builtin_amdgcn_mfma_f32_16x16x32_bf16(pa[1][kk2], vv, o[1][nc], 0, 0, 0);
      }
    }
    __builtin_amdgcn_s_setprio(0);
  }

#pragma unroll
  for (int rs = 0; rs < 2; ++rs) {
    float inv[4];
#pragma unroll
    for (int r = 0; r < 4; ++r) {
      float lr = __shfl(l_s[rs], (lane & 48) + quad * 4 + r);
      inv[r] = 1.0f / lr;
    }
    const size_t orow0 = (size_t)(b * S_LEN + jq[rs] * 64 + wave * 16 + quad * 4);
#pragma unroll
    for (int nc = 0; nc < 8; ++nc)
#pragma unroll
      for (int r = 0; r < 4; ++r)
        aout[(orow0 + r) * 2048 + h * 128 + nc * 16 + l15] =
            __float2bfloat16(o[rs][nc][r] * inv[r]);
  }
}

// -------------------------------------------------------------------- launch
extern "C" void kernel_launch(void* const* d_in, const int* in_sizes, int n_in,
                              void* d_out, int out_size, void* d_ws, size_t ws_size,
                              hipStream_t stream) {
  const float* x    = (const float*)d_in[0];
  const float* cosb = (const float*)d_in[1];
  const float* sinb = (const float*)d_in[2];
  // d_in[3] = mask (causal, analytic)
  const float* Wq = (const float*)d_in[4];
  const float* Wk = (const float*)d_in[5];
  const float* Wv = (const float*)d_in[6];
  const float* Wo = (const float*)d_in[7];
  float* out = (float*)d_out;

  char* ws = (char*)d_ws;
  __hip_bfloat16* xb    = (__hip_bfloat16*)(ws);                 // 16 MB
  __hip_bfloat16* wqkvt = (__hip_bfloat16*)(ws + (16u << 20));   // 12 MB [3072][2048]
  __hip_bfloat16* wot   = (__hip_bfloat16*)(ws + (28u << 20));   // 8 MB  [2048][2048]
  __hip_bfloat16* qbuf  = (__hip_bfloat16*)(ws + (36u << 20));   // 16 MB [4096][2048]
  __hip_bfloat16* kbuf  = (__hip_bfloat16*)(ws + (52u << 20));   // 4 MB  tiles
  __hip_bfloat16* vbuf  = (__hip_bfloat16*)(ws + (56u << 20));   // 4 MB  tiles
  __hip_bfloat16* aout  = (__hip_bfloat16*)(ws + (60u << 20));   // 16 MB [4096][2048]

  prep_kernel<<<10752, 256, 0, stream>>>(x, Wq, Wk, Wv, Wo, xb, wqkvt, wot);
  qkv_gemm_kernel<<<dim3(12, 16), 512, 0, stream>>>(xb, wqkvt, qbuf, kbuf, vbuf, cosb, sinb);
  attn_kernel<<<dim3(16, 32), 256, 0, stream>>>(qbuf, kbuf, vbuf, aout);
  gemm_bt_f32_kernel<<<dim3(16, 16), 512, 0, stream>>>(aout, wot, out, 2048, 2048);
}

// Round 11
// 351.957 us; speedup vs baseline: 1.1328x; 1.0018x over previous
//
#include <hip/hip_runtime.h>
#include <hip/hip_bf16.h>
#include <cstdint>
#include <type_traits>

typedef __attribute__((ext_vector_type(8))) short short8;
typedef __attribute__((ext_vector_type(4))) float floatx4;

constexpr int S_LEN = 2048;
constexpr float ATTN_SCALE = 0.08838834764831845f;  // 128^-0.5
constexpr float LOG2E = 1.4426950408889634f;
constexpr float CP = ATTN_SCALE * LOG2E;            // fold scale into exp2 arg
constexpr float THRR = 5.0f / CP;                   // defer-max threshold (raw units)

// ---------------------------------------------------------------- async G->LDS
__device__ __forceinline__ void gl_lds16(const void* gp, void* lp) {
  __builtin_amdgcn_global_load_lds(
      (__attribute__((address_space(1))) void*)(uintptr_t)gp,
      (__attribute__((address_space(3))) void*)lp,
      16, 0, 0);
}

// --------------------------------------------------------------------- RoPE
__device__ __forceinline__ void rope8(short8 x0, short8 x1, const float* ca,
                                      const float* sa, const float* cb,
                                      const float* sb, short8& y0, short8& y1) {
#pragma unroll
  for (int e = 0; e < 8; ++e) {
    union { short s; __hip_bfloat16 h; } u0, u1, w0, w1;
    u0.s = x0[e]; u1.s = x1[e];
    float f0 = __bfloat162float(u0.h), f1 = __bfloat162float(u1.h);
    int j = e >> 1;
    w0.h = __float2bfloat16(f0 * ca[j] - f1 * sa[j]);
    w1.h = __float2bfloat16(f1 * cb[j] + f0 * sb[j]);
    y0[e] = w0.s; y1[e] = w1.s;
  }
}

// ------------------------------------------------------------- fused prologue
// 64(k) x 64(n) transpose tile: float4 256B row reads, LDS [64][65],
// FULL 128B line writes (32 lanes x short2 per n-row).
__device__ __forceinline__ void tr64(const float* __restrict__ src,
                                     __hip_bfloat16* __restrict__ dst,
                                     int blk, int nblk_x, int N, int tid,
                                     float (*tile)[65]) {
  int n0 = (blk % nblk_x) * 64, k0 = (blk / nblk_x) * 64;
  int tx = tid & 15, ty = tid >> 4;          // (16, 16)
#pragma unroll
  for (int p = 0; p < 4; ++p) {
    int i = ty + p * 16;                     // k-row 0..63
    float4 f = *(const float4*)&src[(size_t)(k0 + i) * N + n0 + tx * 4];
    tile[i][tx * 4 + 0] = f.x;
    tile[i][tx * 4 + 1] = f.y;
    tile[i][tx * 4 + 2] = f.z;
    tile[i][tx * 4 + 3] = f.w;
  }
  __syncthreads();
  int wx = tid & 31, wy = tid >> 5;          // (32, 8)
#pragma unroll
  for (int p = 0; p < 8; ++p) {
    int n = wy + p * 8;                      // n-row 0..63
    union { unsigned u; ushort us[2]; } uu;
    union { __hip_bfloat16 h; ushort us; } h0, h1;
    h0.h = __float2bfloat16(tile[wx * 2 + 0][n]);
    h1.h = __float2bfloat16(tile[wx * 2 + 1][n]);
    uu.us[0] = h0.us; uu.us[1] = h1.us;
    *(unsigned*)&dst[(size_t)(n0 + n) * 2048 + k0 + wx * 2] = uu.u;
  }
}

// blocks [0,8192): x fp32 -> bf16; [8192,9216): Wq^T; [9216,9472): Wk^T;
// [9472,9728): Wv^T; [9728,10752): Wo^T   (64x64 tiles)
__global__ void prep_kernel(const float* __restrict__ x,
                            const float* __restrict__ Wq,
                            const float* __restrict__ Wk,
                            const float* __restrict__ Wv,
                            const float* __restrict__ Wo,
                            __hip_bfloat16* __restrict__ xb,
                            __hip_bfloat16* __restrict__ wqkvt,
                            __hip_bfloat16* __restrict__ wot) {
  __shared__ float tile[64][65];
  int bx = blockIdx.x, tid = threadIdx.x;
  if (bx < 8192) {
    int i = bx * 256 + tid;           // 2097152 float4s exactly
    float4 f = reinterpret_cast<const float4*>(x)[i];
    union { unsigned long long u64; __hip_bfloat16 h[4]; } u;
    u.h[0] = __float2bfloat16(f.x);
    u.h[1] = __float2bfloat16(f.y);
    u.h[2] = __float2bfloat16(f.z);
    u.h[3] = __float2bfloat16(f.w);
    reinterpret_cast<unsigned long long*>(xb)[i] = u.u64;
  } else if (bx < 9216) {
    tr64(Wq, wqkvt, bx - 8192, 32, 2048, tid, tile);
  } else if (bx < 9472) {
    tr64(Wk, wqkvt + 2048 * 2048, bx - 9216, 8, 512, tid, tile);
  } else if (bx < 9728) {
    tr64(Wv, wqkvt + 2560 * 2048, bx - 9472, 8, 512, tid, tile);
  } else {
    tr64(Wo, wot, bx - 9728, 32, 2048, tid, tile);
  }
}

// ===================================================================
// 256x256-tile 8-phase GEMM core (unchanged, proven). BK=64, 8 waves (2Mx4N),
// 128 KiB dbuf LDS, counted vmcnt(4), setprio around MFMA clusters.
// ===================================================================
__device__ __forceinline__ void gemm256_core(
    const __hip_bfloat16* __restrict__ Ab,   // A + m0*K, row-major [.][K]
    const __hip_bfloat16* __restrict__ Bb,   // Bt + n0*K, row-major [.][K]
    const int K, __hip_bfloat16* lds, floatx4 (&acc)[8][4]) {
  const int tid = threadIdx.x;
  const int wave = tid >> 6, lane = tid & 63;
  const int quad = lane >> 4, l15 = lane & 15;
  const int wm = wave >> 2, wn = wave & 3;
  const int nt = K >> 6;
  const int u2 = wave * 2;

  auto stA = [&](int tt, int h) {
    __hip_bfloat16* dst = lds + (tt & 1) * 32768;
    const int k0 = tt << 6;
#pragma unroll
    for (int j = 0; j < 2; ++j) {
      const int kc = (u2 + j) >> 1, rb = (u2 + j) & 1;
      gl_lds16(Ab + (size_t)(h * 128 + rb * 64 + lane) * K + k0 + kc * 8,
               dst + (kc * 256 + h * 128 + rb * 64) * 8);
    }
  };
  auto stB = [&](int tt, int h) {
    __hip_bfloat16* dst = lds + (tt & 1) * 32768 + 16384;
    const int k0 = tt << 6;
#pragma unroll
    for (int j = 0; j < 2; ++j) {
      const int kc = (u2 + j) >> 1, rb = (u2 + j) & 1;
      gl_lds16(Bb + (size_t)(h * 128 + rb * 64 + lane) * K + k0 + kc * 8,
               dst + (kc * 256 + h * 128 + rb * 64) * 8);
    }
  };

  // prologue: tile0 fully + tile1 B halves (A1 staged in tile0 ph0/ph1)
  stA(0, 0); stA(0, 1); stB(0, 0); stB(0, 1);
  if (nt > 1) { stB(1, 0); stB(1, 1); }
  asm volatile("s_waitcnt vmcnt(4)" ::: "memory");   // tile0's 8 loads landed
  __builtin_amdgcn_s_barrier();

  const int abase = (quad * 256 + wm * 128 + l15) * 8;
  const int bbase = (quad * 256 + wn * 64 + l15) * 8;

#pragma unroll 2
  for (int t = 0; t < nt; ++t) {
    const __hip_bfloat16* Al = lds + (t & 1) * 32768;
    const __hip_bfloat16* Bl = Al + 16384;
    short8 b[2][4];
#pragma unroll
    for (int q = 0; q < 4; ++q) {
      short8 a[2][2];
#pragma unroll
      for (int kk = 0; kk < 2; ++kk) {
        if (q == 0) {
#pragma unroll
          for (int ni = 0; ni < 4; ++ni)
            b[kk][ni] = *(const short8*)&Bl[kk * 8192 + bbase + ni * 128];
        }
#pragma unroll
        for (int mi = 0; mi < 2; ++mi)
          a[kk][mi] = *(const short8*)&Al[kk * 8192 + abase + (2 * q + mi) * 128];
      }
      if (q == 0)      { if (t + 1 < nt) stA(t + 1, 0); }
      else if (q == 1) { if (t + 1 < nt) stA(t + 1, 1); }
      else if (q == 2) { if (t + 2 < nt) stB(t + 2, 0); }
      else             { if (t + 2 < nt) stB(t + 2, 1); }
      __builtin_amdgcn_s_barrier();
      asm volatile("s_waitcnt lgkmcnt(0)" ::: "memory");
      __builtin_amdgcn_sched_barrier(0);    // rule #18: pin reads above MFMAs
      __builtin_amdgcn_s_setprio(1);
#pragma unroll
      for (int kk = 0; kk < 2; ++kk)
#pragma unroll
        for (int mi = 0; mi < 2; ++mi)
#pragma unroll
          for (int ni = 0; ni < 4; ++ni)
            acc[2 * q + mi][ni] = __builtin_amdgcn_mfma_f32_16x16x32_bf16(
                a[kk][mi], b[kk][ni], acc[2 * q + mi][ni], 0, 0, 0);
      __builtin_amdgcn_s_setprio(0);
      if (q == 3) {
        if (t + 2 < nt) asm volatile("s_waitcnt vmcnt(4)" ::: "memory");
        else            asm volatile("s_waitcnt vmcnt(0)" ::: "memory");
      }
      __builtin_amdgcn_s_barrier();
    }
  }
  asm volatile("" ::: "memory");   // fence before LDS reuse in epilogue
}

// ===================================================================
// 256x128-tile 2-phase GEMM core (unchanged, proven).
// ===================================================================
__device__ __forceinline__ void gemm_256x128_core(
    const __hip_bfloat16* __restrict__ Ab,
    const __hip_bfloat16* __restrict__ Bb,
    const int K, __hip_bfloat16* lds, floatx4 (&acc)[4][4]) {
  const int tid = threadIdx.x;
  const int wave = tid >> 6, lane = tid & 63;
  const int quad = lane >> 4, l15 = lane & 15;
  const int wm = wave >> 1, wn = wave & 1;
  const int nt = K >> 6;

  auto stA = [&](int tt, int c) {     // c in 0..3
    __hip_bfloat16* dst = lds + (tt & 1) * 24576;
    const int k0 = tt << 6;
    const int i = c * 8 + wave;       // 0..31: kc = i>>2, rowblk = i&3
    const int kc = i >> 2, rb = i & 3;
    gl_lds16(Ab + (size_t)(rb * 64 + lane) * K + k0 + kc * 8,
             dst + (kc * 256 + rb * 64) * 8);
  };
  auto stB = [&](int tt, int c) {     // c in 0..1
    __hip_bfloat16* dst = lds + (tt & 1) * 24576 + 16384;
    const int k0 = tt << 6;
    const int i = c * 8 + wave;       // 0..15: kc = i>>1, rowblk = i&1
    const int kc = i >> 1, rb = i & 1;
    gl_lds16(Bb + (size_t)(rb * 64 + lane) * K + k0 + kc * 8,
             dst + (kc * 128 + rb * 64) * 8);
  };

  stA(0, 0); stA(0, 1); stA(0, 2); stA(0, 3);
  stB(0, 0); stB(0, 1);
  if (nt > 1) {
    stB(1, 0); stB(1, 1);
    asm volatile("s_waitcnt vmcnt(2)" ::: "memory");
  } else {
    asm volatile("s_waitcnt vmcnt(0)" ::: "memory");
  }
  __builtin_amdgcn_s_barrier();

  const int abase = (quad * 256 + wm * 64 + l15) * 8;
  const int bbase = (quad * 128 + wn * 64 + l15) * 8;

#pragma unroll 2
  for (int t = 0; t < nt; ++t) {
    const __hip_bfloat16* Al = lds + (t & 1) * 24576;
    const __hip_bfloat16* Bl = Al + 16384;
    short8 b[2][4], a[2][2];
    // ---- phase 0: mi 0,1 (B frags read once per tile, reused in ph1)
#pragma unroll
    for (int kk = 0; kk < 2; ++kk) {
#pragma unroll
      for (int ni = 0; ni < 4; ++ni)
        b[kk][ni] = *(const short8*)&Bl[kk * 4096 + bbase + ni * 128];
#pragma unroll
      for (int mi = 0; mi < 2; ++mi)
        a[kk][mi] = *(const short8*)&Al[kk * 8192 + abase + mi * 128];
    }
    if (t + 1 < nt) { stA(t + 1, 0); stA(t + 1, 1); }
    __builtin_amdgcn_s_barrier();
    asm volatile("s_waitcnt lgkmcnt(0)" ::: "memory");
    __builtin_amdgcn_sched_barrier(0);
    __builtin_amdgcn_s_setprio(1);
#pragma unroll
    for (int kk = 0; kk < 2; ++kk)
#pragma unroll
      for (int mi = 0; mi < 2; ++mi)
#pragma unroll
        for (int ni = 0; ni < 4; ++ni)
          acc[mi][ni] = __builtin_amdgcn_mfma_f32_16x16x32_bf16(
              a[kk][mi], b[kk][ni], acc[mi][ni], 0, 0, 0);
    __builtin_amdgcn_s_setprio(0);
    __builtin_amdgcn_s_barrier();
    // ---- phase 1: mi 2,3
#pragma unroll
    for (int kk = 0; kk < 2; ++kk)
#pragma unroll
      for (int mi = 0; mi < 2; ++mi)
        a[kk][mi] = *(const short8*)&Al[kk * 8192 + abase + (2 + mi) * 128];
    if (t + 1 < nt) { stA(t + 1, 2); stA(t + 1, 3); }
    if (t + 2 < nt) { stB(t + 2, 0); stB(t + 2, 1); }
    __builtin_amdgcn_s_barrier();
    asm volatile("s_waitcnt lgkmcnt(0)" ::: "memory");
    __builtin_amdgcn_sched_barrier(0);
    __builtin_amdgcn_s_setprio(1);
#pragma unroll
    for (int kk = 0; kk < 2; ++kk)
#pragma unroll
      for (int mi = 0; mi < 2; ++mi)
#pragma unroll
        for (int ni = 0; ni < 4; ++ni)
          acc[2 + mi][ni] = __builtin_amdgcn_mfma_f32_16x16x32_bf16(
              a[kk][mi], b[kk][ni], acc[2 + mi][ni], 0, 0, 0);
    __builtin_amdgcn_s_setprio(0);
    if (t + 2 < nt) asm volatile("s_waitcnt vmcnt(2)" ::: "memory");
    else            asm volatile("s_waitcnt vmcnt(0)" ::: "memory");
    __builtin_amdgcn_s_barrier();
  }
  asm volatile("" ::: "memory");
}

// ------------------------------------------------------------ QKV GEMM (fused)
// 1-D grid 192, XCD-aware: XCD x owns a 3(bx) x 8(by) chunk -> its 3 B-panels
// (3 MB) stay L2-resident instead of 14 MB scattered.
__global__ __launch_bounds__(512, 2) void qkv_gemm_kernel(
    const __hip_bfloat16* __restrict__ A,
    const __hip_bfloat16* __restrict__ Bt,
    __hip_bfloat16* __restrict__ qbuf,
    __hip_bfloat16* __restrict__ kbuf,
    __hip_bfloat16* __restrict__ vbuf,
    const float* __restrict__ cosb,
    const float* __restrict__ sinb) {
  constexpr int K = 2048;
  __shared__ __align__(16) __hip_bfloat16 lds[65536];  // 128 KiB
  const int tid = threadIdx.x;
  const int f = blockIdx.x;                  // 0..191
  const int xcd = f & 7, i = f >> 3;         // i in 0..23
  const int bxt = (xcd & 3) * 3 + i % 3;     // 0..11
  const int byt = (xcd >> 2) * 8 + i / 3;    // 0..15
  const int m0 = byt * 256, n0 = bxt * 256;

  floatx4 acc[8][4] = {};
  gemm256_core(A + (size_t)m0 * K, Bt + (size_t)n0 * K, K, lds, acc);

  const int wave = tid >> 6, lane = tid & 63;
  const int quad = lane >> 4, l15 = lane & 15;
  const int wm = wave >> 2, wn = wave & 3;
  const bool isv = (n0 >= 2560);
  short* lds2 = (short*)lds;                       // [256][256] bf16 = 128 KB
#pragma unroll
  for (int mi = 0; mi < 8; ++mi)
#pragma unroll
    for (int ni = 0; ni < 4; ++ni)
#pragma unroll
      for (int r = 0; r < 4; ++r) {
        int row = wm * 128 + mi * 16 + quad * 4 + r;  // C/D: row = quad*4+reg
        int col = wn * 64 + ni * 16 + l15;            //      col = lane&15
        union { short s; __hip_bfloat16 h; } u;
        u.h = __float2bfloat16(acc[mi][ni][r]);
        if (isv) lds2[col * 256 + row] = u.s;         // V stored transposed
        else     lds2[row * 256 + col] = u.s;
      }
  __syncthreads();

  const int c16 = tid & 15, hh = c16 >> 3, c8 = c16 & 7;
  const int rid = tid >> 4, d0 = c8 * 8;
  if (n0 < 2048) {
    // ---- Q: rope + row-major coalesced write (2 heads per tile)
#pragma unroll
    for (int j = 0; j < 8; ++j) {
      int rr = rid + 32 * j;
      int rowg = m0 + rr;
      int s = rowg & (S_LEN - 1);
      float ca[4], sa[4], cb[4], sb[4];
      *(float4*)ca = *(const float4*)&cosb[s * 64 + c8 * 4];
      *(float4*)sa = *(const float4*)&sinb[s * 64 + c8 * 4];
      *(float4*)cb = *(const float4*)&cosb[s * 64 + 32 + c8 * 4];
      *(float4*)sb = *(const float4*)&sinb[s * 64 + 32 + c8 * 4];
      short8 x0 = *(const short8*)&lds2[rr * 256 + hh * 128 + d0];
      short8 x1 = *(const short8*)&lds2[rr * 256 + hh * 128 + 64 + d0];
      short8 y0, y1;
      rope8(x0, x1, ca, sa, cb, sb, y0, y1);
      *(short8*)(qbuf + (size_t)rowg * 2048 + n0 + hh * 128 + d0) = y0;
      *(short8*)(qbuf + (size_t)rowg * 2048 + n0 + hh * 128 + 64 + d0) = y1;
    }
  } else if (!isv) {
    // ---- K: rope + chunk-transposed tile write (2 kv-heads per tile)
    const int kvh = ((n0 - 2048) >> 7) + hh;
#pragma unroll
    for (int j = 0; j < 8; ++j) {
      int rr = rid + 32 * j;
      int rowg = m0 + rr;
      int s = rowg & (S_LEN - 1), bb = rowg >> 11;
      int kv = s & 63;
      size_t tb = ((size_t)(bb * 4 + kvh) * 32 + (s >> 6)) * 8192;
      float ca[4], sa[4], cb[4], sb[4];
      *(float4*)ca = *(const float4*)&cosb[s * 64 + c8 * 4];
      *(float4*)sa = *(const float4*)&sinb[s * 64 + c8 * 4];
      *(float4*)cb = *(const float4*)&cosb[s * 64 + 32 + c8 * 4];
      *(float4*)sb = *(const float4*)&sinb[s * 64 + 32 + c8 * 4];
      short8 x0 = *(const short8*)&lds2[rr * 256 + hh * 128 + d0];
      short8 x1 = *(const short8*)&lds2[rr * 256 + hh * 128 + 64 + d0];
      short8 y0, y1;
      rope8(x0, x1, ca, sa, cb, sb, y0, y1);
      *(short8*)(kbuf + tb + (size_t)c8 * 512 + kv * 8) = y0;
      *(short8*)(kbuf + tb + (size_t)(8 + c8) * 512 + kv * 8) = y1;
    }
  } else {
    // ---- V: transposed XOR-swizzled tile write (matches attn PV reads)
    const int kvh = ((n0 - 2560) >> 7) + hh;
    const int bb = m0 >> 11;
    const int kt0 = (m0 & (S_LEN - 1)) >> 6;
    const int kv0 = c8 * 8;
#pragma unroll
    for (int j = 0; j < 4; ++j) {
      int d = rid + 32 * j;            // 0..127 within head
      int cxor = (d & 7) << 3;
#pragma unroll
      for (int half = 0; half < 4; ++half) {
        short8 vv = *(const short8*)&lds2[(hh * 128 + d) * 256 + half * 64 + kv0];
        size_t tb = ((size_t)(bb * 4 + kvh) * 32 + kt0 + half) * 8192;
        *(short8*)(vbuf + tb + d * 64 + (kv0 ^ cxor)) = vv;
      }
    }
  }
}

// --------------------------------------------------------------- AO GEMM
// 1-D grid 256, XCD-aware: XCD x owns a 4(bx) x 8(by) chunk -> its 4 B-panels
// (2 MB) stay L2-resident.
__global__ __launch_bounds__(512, 2) void gemm_bt_f32_kernel(
    const __hip_bfloat16* __restrict__ A,
    const __hip_bfloat16* __restrict__ Bt,
    float* __restrict__ C, int N, int K) {
  __shared__ __align__(16) __hip_bfloat16 lds[49152];  // 96 KiB
  const int tid = threadIdx.x;
  const int f = blockIdx.x;                  // 0..255
  const int xcd = f & 7, i = f >> 3;         // i in 0..31
  const int bxt = (xcd & 3) * 4 + (i & 3);   // 0..15
  const int byt = (xcd >> 2) * 8 + (i >> 2); // 0..15
  const int m0 = byt * 256, n0 = bxt * 128;

  floatx4 acc[4][4] = {};
  gemm_256x128_core(A + (size_t)m0 * K, Bt + (size_t)n0 * K, K, lds, acc);

  const int wave = tid >> 6, lane = tid & 63;
  const int quad = lane >> 4, l15 = lane & 15;
  const int wm = wave >> 1, wn = wave & 1;
#pragma unroll
  for (int mi = 0; mi < 4; ++mi)
#pragma unroll
    for (int ni = 0; ni < 4; ++ni)
#pragma unroll
      for (int r = 0; r < 4; ++r) {
        int row = m0 + wm * 64 + mi * 16 + quad * 4 + r;
        int col = n0 + wn * 64 + ni * 16 + l15;
        C[(size_t)row * N + col] = acc[mi][ni][r];
      }
}

// ---------------------------------------------------------------- attention
// v6 DUAL-ENDED (proven 87.8 us) + XCD-aware mapping: 1-D grid 512; XCD x
// owns bh in {4x..4x+3} x all j -> exactly ONE 1 MB K/V panel per XCD L2
// (old j%8 mapping put all 8 panels = 8 MB on every XCD -> thrash).
__global__ __launch_bounds__(256, 2) void attn_kernel(
    const __hip_bfloat16* __restrict__ qbuf,   // [4096][2048]
    const __hip_bfloat16* __restrict__ kbuf,   // tiles
    const __hip_bfloat16* __restrict__ vbuf,   // tiles
    __hip_bfloat16* __restrict__ aout) {       // [4096][2048]
  const int f = blockIdx.x;                    // 0..511
  const int xcd = f & 7, ii = f >> 3;          // ii in 0..63
  const int bh = xcd * 4 + (ii >> 4);          // 0..31
  const int j = ii & 15;                       // 0..15
  const int b = bh >> 4, h = bh & 15;
  const int kvh = h >> 2;
  const int jq[2] = {j, 31 - j};               // 64-row q-tiles (both ends)

  __shared__ __align__(16) __hip_bfloat16 Kbuf[2][8192];      // 2 x 16 KB
  __shared__ __align__(16) __hip_bfloat16 Vbuf[2][8192];      // 2 x 16 KB

  const int tid = threadIdx.x;
  const int wave = tid >> 6, lane = tid & 63;
  const int quad = lane >> 4, l15 = lane & 15;

  short8 qfrag[2][4];
#pragma unroll
  for (int rs = 0; rs < 2; ++rs)
#pragma unroll
    for (int kc = 0; kc < 4; ++kc)
      qfrag[rs][kc] = *(const short8*)(qbuf +
          (size_t)(b * S_LEN + jq[rs] * 64 + wave * 16 + l15) * 2048 +
          h * 128 + kc * 32 + quad * 8);

  const __hip_bfloat16* ktiles = kbuf + (size_t)(b * 4 + kvh) * 32 * 8192;
  const __hip_bfloat16* vtiles = vbuf + (size_t)(b * 4 + kvh) * 32 * 8192;
  const int nt = 32 - j;   // rowset1 needs kv tiles 0..31-j

#pragma unroll
  for (int jj = 0; jj < 4; ++jj) {
    int c = tid + 256 * jj;
    gl_lds16(ktiles + c * 8, &Kbuf[0][c * 8]);
    gl_lds16(vtiles + c * 8, &Vbuf[0][c * 8]);
  }

  float m_s[2] = {-1e30f, -1e30f};
  float l_s[2] = {0.f, 0.f};
  floatx4 o[2][8] = {};

  for (int kt = 0; kt < nt; ++kt) {
    const int cur = kt & 1;
    __syncthreads();   // K(kt)/V(kt) DMA drained & visible

    if (kt + 1 < nt) {
      const __hip_bfloat16* kb = ktiles + (size_t)(kt + 1) * 8192;
      const __hip_bfloat16* vb = vtiles + (size_t)(kt + 1) * 8192;
#pragma unroll
      for (int jj = 0; jj < 4; ++jj) {
        int c = tid + 256 * jj;
        gl_lds16(kb + c * 8, &Kbuf[1 - cur][c * 8]);
        gl_lds16(vb + c * 8, &Vbuf[1 - cur][c * 8]);
      }
    }

    const bool do0 = (kt <= j);   // rowset0 fully masked beyond its diagonal

    // S' = K Q^T (swapped): sc[rs][ni][r] = S[kv=kt*64+ni*16+quad*4+r][q=l15]
    floatx4 sc[2][4] = {};
#pragma unroll
    for (int ni = 0; ni < 4; ++ni)
#pragma unroll
      for (int kc = 0; kc < 4; ++kc) {
        short8 bf = *(const short8*)&Kbuf[cur][((kc * 4 + quad) * 64 + ni * 16 + l15) * 8];
        if (do0)
          sc[0][ni] = __builtin_amdgcn_mfma_f32_16x16x32_bf16(bf, qfrag[0][kc], sc[0][ni], 0, 0, 0);
        sc[1][ni] = __builtin_amdgcn_mfma_f32_16x16x32_bf16(bf, qfrag[1][kc], sc[1][ni], 0, 0, 0);
      }

    short8 pa[2][2];
#pragma unroll
    for (int rs = 0; rs < 2; ++rs) {
      if (rs == 0 && !do0) continue;
      if (kt >= jq[rs]) {   // diagonal tile: causal mask
        const int qg = jq[rs] * 64 + wave * 16 + l15;
#pragma unroll
        for (int ni = 0; ni < 4; ++ni) {
          int kvb = kt * 64 + ni * 16 + quad * 4;
#pragma unroll
          for (int r = 0; r < 4; ++r)
            if (kvb + r > qg) sc[rs][ni][r] = -1e30f;
        }
      }

      // per-lane row max over this tile's 64 kv
      float v = sc[rs][0][0];
#pragma unroll
      for (int ni = 0; ni < 4; ++ni)
#pragma unroll
        for (int r = 0; r < 4; ++r) v = fmaxf(v, sc[rs][ni][r]);
      v = fmaxf(v, __shfl_xor(v, 16));
      v = fmaxf(v, __shfl_xor(v, 32));

      float mold = m_s[rs];
      if (__any(v > mold + THRR)) {      // defer-max: rescale only when needed
        float mnew = fmaxf(mold, v);
        float alpha = exp2f((mold - mnew) * CP);
        m_s[rs] = mnew;
        l_s[rs] *= alpha;
        float ar[4];
#pragma unroll
        for (int r = 0; r < 4; ++r)
          ar[r] = __shfl(alpha, (lane & 48) + quad * 4 + r);
#pragma unroll
        for (int nc = 0; nc < 8; ++nc)
#pragma unroll
          for (int r = 0; r < 4; ++r) o[rs][nc][r] *= ar[r];
      }

      float mc = m_s[rs] * CP;
      unsigned pk[4][2];
      float lsum = 0.f;
#pragma unroll
      for (int ni = 0; ni < 4; ++ni)
#pragma unroll
        for (int pr = 0; pr < 2; ++pr) {
          float p0 = exp2f(sc[rs][ni][2 * pr] * CP - mc);
          float p1 = exp2f(sc[rs][ni][2 * pr + 1] * CP - mc);
          lsum += p0 + p1;
          union { unsigned u; ushort us[2]; } uu;
          union { __hip_bfloat16 h; ushort us; } b0, b1;
          b0.h = __float2bfloat16(p0); b1.h = __float2bfloat16(p1);
          uu.us[0] = b0.us; uu.us[1] = b1.us;
          pk[ni][pr] = uu.u;
        }
      lsum += __shfl_xor(lsum, 16);
      lsum += __shfl_xor(lsum, 32);
      l_s[rs] += lsum;

      // quad-redistribution: pk[ni][pr]@lane(qs,l15) -> A-frag P[q=l15][kv]
#pragma unroll
      for (int kk2 = 0; kk2 < 2; ++kk2) {
        union { unsigned w[4]; short8 s; } pw_;
#pragma unroll
        for (int jj = 0; jj < 4; ++jj) {
          int src = ((((quad & 1) * 2) + (jj >> 1)) << 4) | l15;
          unsigned lo = (unsigned)__shfl((int)pk[2 * kk2][jj & 1], src);
          unsigned hi = (unsigned)__shfl((int)pk[2 * kk2 + 1][jj & 1], src);
          pw_.w[jj] = (quad >> 1) ? hi : lo;
        }
        pa[rs][kk2] = pw_.s;
      }
    }

    // fused PV: each V fragment loaded once, used by active rowsets
    __builtin_amdgcn_s_setprio(1);
#pragma unroll
    for (int kk2 = 0; kk2 < 2; ++kk2) {
#pragma unroll
      for (int nc = 0; nc < 8; ++nc) {
        int d = nc * 16 + l15;
        int swcol = (kk2 * 32 + quad * 8) ^ ((d & 7) << 3);
        short8 vv = *(const short8*)&Vbuf[cur][d * 64 + swcol];
        if (do0)
          o[0][nc] = __builtin_amdgcn_mfma_f32_16x16x32_bf16(pa[0][kk2], vv, o[0][nc], 0, 0, 0);
        o[1][nc] = __builtin_amdgcn_mfma_f32_16x16x32_bf16(pa[1][kk2], vv, o[1][nc], 0, 0, 0);
      }
    }
    __builtin_amdgcn_s_setprio(0);
  }

#pragma unroll
  for (int rs = 0; rs < 2; ++rs) {
    float inv[4];
#pragma unroll
    for (int r = 0; r < 4; ++r) {
      float lr = __shfl(l_s[rs], (lane & 48) + quad * 4 + r);
      inv[r] = 1.0f / lr;
    }
    const size_t orow0 = (size_t)(b * S_LEN + jq[rs] * 64 + wave * 16 + quad * 4);
#pragma unroll
    for (int nc = 0; nc < 8; ++nc)
#pragma unroll
      for (int r = 0; r < 4; ++r)
        aout[(orow0 + r) * 2048 + h * 128 + nc * 16 + l15] =
            __float2bfloat16(o[rs][nc][r] * inv[r]);
  }
}

// -------------------------------------------------------------------- launch
extern "C" void kernel_launch(void* const* d_in, const int* in_sizes, int n_in,
                              void* d_out, int out_size, void* d_ws, size_t ws_size,
                              hipStream_t stream) {
  const float* x    = (const float*)d_in[0];
  const float* cosb = (const float*)d_in[1];
  const float* sinb = (const float*)d_in[2];
  // d_in[3] = mask (causal, analytic)
  const float* Wq = (const float*)d_in[4];
  const float* Wk = (const float*)d_in[5];
  const float* Wv = (const float*)d_in[6];
  const float* Wo = (const float*)d_in[7];
  float* out = (float*)d_out;

  char* ws = (char*)d_ws;
  __hip_bfloat16* xb    = (__hip_bfloat16*)(ws);                 // 16 MB
  __hip_bfloat16* wqkvt = (__hip_bfloat16*)(ws + (16u << 20));   // 12 MB [3072][2048]
  __hip_bfloat16* wot   = (__hip_bfloat16*)(ws + (28u << 20));   // 8 MB  [2048][2048]
  __hip_bfloat16* qbuf  = (__hip_bfloat16*)(ws + (36u << 20));   // 16 MB [4096][2048]
  __hip_bfloat16* kbuf  = (__hip_bfloat16*)(ws + (52u << 20));   // 4 MB  tiles
  __hip_bfloat16* vbuf  = (__hip_bfloat16*)(ws + (56u << 20));   // 4 MB  tiles
  __hip_bfloat16* aout  = (__hip_bfloat16*)(ws + (60u << 20));   // 16 MB [4096][2048]

  prep_kernel<<<10752, 256, 0, stream>>>(x, Wq, Wk, Wv, Wo, xb, wqkvt, wot);
  qkv_gemm_kernel<<<192, 512, 0, stream>>>(xb, wqkvt, qbuf, kbuf, vbuf, cosb, sinb);
  attn_kernel<<<512, 256, 0, stream>>>(qbuf, kbuf, vbuf, aout);
  gemm_bt_f32_kernel<<<256, 512, 0, stream>>>(aout, wot, out, 2048, 2048);
}